// Round 1
// baseline (1614.606 us; speedup 1.0000x reference)
//
#include <hip/hip_runtime.h>
#include <math.h>

#define NB 2
#define CIN 64
#define H0 96
#define W0 96
#define HH 192
#define WW 192
#define LL (HH*WW)        // 36864
#define NHASH 4
#define CHK 144
#define NCHK 256          // LL/CHK
#define CE 16
#define CV 64
#define NBUCK 128
#define SEGL 576
#define NSEG 64           // LL/SEGL
#define JT 48
#define NT 9              // 432/48

__device__ __forceinline__ unsigned short f2bf(float f){
  unsigned int u = __float_as_uint(f);
  u += 0x7fffu + ((u >> 16) & 1u);
  return (unsigned short)(u >> 16);
}
__device__ __forceinline__ float bfl(unsigned int u){ return __uint_as_float(u << 16); }
__device__ __forceinline__ float bfh(unsigned int u){ return __uint_as_float(u & 0xffff0000u); }

// ---------------- bicubic 2x upsample (separable, edge pad) ----------------
__global__ __launch_bounds__(256) void k_upsample(const float* __restrict__ x,
                                                  float* __restrict__ out){
  int idx = blockIdx.x*256 + threadIdx.x;
  if (idx >= NB*CIN*HH*WW) return;
  int ox = idx % WW; int t2 = idx / WW;
  int oy = t2 % HH;  t2 /= HH;           // t2 = n*CIN + c
  int i = oy >> 1, a = oy & 1;
  int j = ox >> 1, b = ox & 1;
  const float e0=-0.03515625f, e1=0.26171875f, e2=0.87890625f, e3=-0.10546875f;
  float wy[4], wx[4]; int ty[4], tx[4];
  if (a){ wy[0]=e3; wy[1]=e2; wy[2]=e1; wy[3]=e0; } else { wy[0]=e0; wy[1]=e1; wy[2]=e2; wy[3]=e3; }
  if (b){ wx[0]=e3; wx[1]=e2; wx[2]=e1; wx[3]=e0; } else { wx[0]=e0; wx[1]=e1; wx[2]=e2; wx[3]=e3; }
  int offy = a ? -1 : -2, offx = b ? -1 : -2;
  #pragma unroll
  for (int k=0;k<4;k++){
    int t = i + offy + k; ty[k] = t<0?0:(t>H0-1?H0-1:t);
    int s = j + offx + k; tx[k] = s<0?0:(s>W0-1?W0-1:s);
  }
  const float* xp = x + (size_t)t2*H0*W0;
  float s = 0.f;
  #pragma unroll
  for (int ky=0;ky<4;ky++){
    const float* row = xp + ty[ky]*W0;
    float rs = 0.f;
    rs = fmaf(wx[0], row[tx[0]], rs);
    rs = fmaf(wx[1], row[tx[1]], rs);
    rs = fmaf(wx[2], row[tx[2]], rs);
    rs = fmaf(wx[3], row[tx[3]], rs);
    s = fmaf(wy[ky], rs, s);
  }
  out[idx] = s;
}

// ---------------- direct 3x3 conv, pad 1 -----------------------------------
// block 128 thr, tile 32(W)x16(H), 16 out-ch per block, 2x2 px per thread
template<int CO_TOT, bool RELU, bool OUT_NLC>
__global__ __launch_bounds__(128) void k_conv3(const float* __restrict__ in,
    const float* __restrict__ wgt, const float* __restrict__ bias,
    float* __restrict__ out){
  __shared__ float in_t[4][18][36];
  __shared__ float wt[4][9][16];
  const int t = threadIdx.x;
  const int bx = blockIdx.x, by = blockIdx.y, bz = blockIdx.z;
  constexpr int NCOG = CO_TOT/16;
  const int cog = bz % NCOG;
  const int n = bz / NCOG;
  const int co0 = cog*16;
  const int tx = t & 15, ty = t >> 4;
  const int px0 = tx*2, py0 = ty*2;
  const int gx0 = bx*32, gy0 = by*16;
  float acc[16][4];
  #pragma unroll
  for (int c=0;c<16;c++){ acc[c][0]=0.f; acc[c][1]=0.f; acc[c][2]=0.f; acc[c][3]=0.f; }
  for (int ci0=0; ci0<CIN; ci0+=4){
    for (int e=t; e<4*18*34; e+=128){
      int ci = e/(18*34); int rem = e - ci*(18*34);
      int r = rem/34; int cx = rem - r*34;
      int gy = gy0 + r - 1, gx = gx0 + cx - 1;
      float v = 0.f;
      if (gy>=0 && gy<HH && gx>=0 && gx<WW)
        v = in[(((size_t)n*CIN + ci0+ci)*HH + gy)*WW + gx];
      in_t[ci][r][cx] = v;
    }
    for (int e=t; e<4*9*16; e+=128){
      int ci = e/144; int rem = e - ci*144;
      int kk = rem >> 4; int co = rem & 15;
      wt[ci][kk][co] = wgt[(((size_t)(co0+co))*CIN + ci0+ci)*9 + kk];
    }
    __syncthreads();
    #pragma unroll
    for (int ci=0; ci<4; ci++){
      #pragma unroll
      for (int ky=0; ky<3; ky++){
        float v0=in_t[ci][py0+ky][px0+0], v1=in_t[ci][py0+ky][px0+1],
              v2=in_t[ci][py0+ky][px0+2], v3=in_t[ci][py0+ky][px0+3];
        float u0=in_t[ci][py0+ky+1][px0+0], u1=in_t[ci][py0+ky+1][px0+1],
              u2=in_t[ci][py0+ky+1][px0+2], u3=in_t[ci][py0+ky+1][px0+3];
        #pragma unroll
        for (int kx=0; kx<3; kx++){
          float a0 = (kx==0)?v0:((kx==1)?v1:v2);
          float a1 = (kx==0)?v1:((kx==1)?v2:v3);
          float b0 = (kx==0)?u0:((kx==1)?u1:u2);
          float b1 = (kx==0)?u1:((kx==1)?u2:u3);
          #pragma unroll
          for (int c=0;c<16;c++){
            float wv = wt[ci][ky*3+kx][c];
            acc[c][0] = fmaf(a0, wv, acc[c][0]);
            acc[c][1] = fmaf(a1, wv, acc[c][1]);
            acc[c][2] = fmaf(b0, wv, acc[c][2]);
            acc[c][3] = fmaf(b1, wv, acc[c][3]);
          }
        }
      }
    }
    __syncthreads();
  }
  #pragma unroll
  for (int c=0;c<16;c++){
    float bv = bias[co0+c];
    #pragma unroll
    for (int p=0;p<4;p++){
      int iy = p>>1, ix = p&1;
      float vv = acc[c][p] + bv;
      if (RELU) vv = fmaxf(vv, 0.f);
      int yy = gy0+py0+iy, xx = gx0+px0+ix;
      if (OUT_NLC)
        out[((size_t)n*LL + yy*WW+xx)*16 + c] = vv;
      else
        out[(((size_t)n*CO_TOT + co0+c)*HH + yy)*WW + xx] = vv;
    }
  }
}

// ---------------- 1x1 conv (ye), output [N][L][64] --------------------------
__global__ __launch_bounds__(256) void k_conv1x1(const float* __restrict__ x2,
    const float* __restrict__ wa, const float* __restrict__ ba,
    float* __restrict__ ye){
  __shared__ float xs[64][64];
  __shared__ float wts[64][64];
  const int t = threadIdx.x;
  const int n = blockIdx.y;
  const int l0 = blockIdx.x*64;
  for (int e=t; e<4096; e+=256){
    int ci = e >> 6, l = e & 63;
    xs[ci][l]  = x2[((size_t)n*CIN+ci)*LL + l0 + l];
    wts[ci][l] = wa[(size_t)l*64 + ci];          // wts[ci][co]
  }
  __syncthreads();
  const int l = t & 63, cq = t >> 6;
  float acc[16];
  #pragma unroll
  for (int i=0;i<16;i++) acc[i] = ba[cq*16+i];
  for (int ci=0; ci<64; ci++){
    float xv = xs[ci][l];
    #pragma unroll
    for (int i=0;i<16;i++) acc[i] = fmaf(xv, wts[ci][cq*16+i], acc[i]);
  }
  float* op = &ye[((size_t)n*LL + l0 + l)*64 + cq*16];
  #pragma unroll
  for (int i=0;i<16;i++) op[i] = acc[i];
}

// ---------------- LSH codes: argmax over [rot ; -rot] ------------------------
__global__ __launch_bounds__(128) void k_codes(const float* __restrict__ xe,
    const float* __restrict__ rot, unsigned char* __restrict__ codes){
  __shared__ float rs[NHASH][64][16];
  const int t = threadIdx.x;
  for (int e=t; e<4096; e+=128){
    int f = e >> 8; int rem = e & 255;
    int h = rem >> 6; int i = rem & 63;
    rs[h][i][f] = rot[((size_t)f*NHASH + h)*64 + i];
  }
  __syncthreads();
  const int n = blockIdx.y;
  const int l = blockIdx.x*128 + t;
  float q[16];
  const float* xr = &xe[((size_t)n*LL + l)*16];
  #pragma unroll
  for (int f=0;f<16;f++) q[f] = xr[f];
  #pragma unroll
  for (int h=0;h<NHASH;h++){
    float bp = -3.0e38f, bn = -3.0e38f; int ap=0, an=0;
    for (int i=0;i<64;i++){
      float s = 0.f;
      #pragma unroll
      for (int f=0;f<16;f++) s = fmaf(q[f], rs[h][i][f], s);
      if (s > bp){ bp = s; ap = i; }
      if (-s > bn){ bn = -s; an = i; }
    }
    int code = (bp >= bn) ? ap : (64 + an);   // first-index tie rule of argmax
    codes[((size_t)n*NHASH + h)*LL + l] = (unsigned char)code;
  }
}

// ---------------- stable counting sort: hist / scan / rank+scatter ----------
__global__ __launch_bounds__(256) void k_hist(const unsigned char* __restrict__ codes,
    unsigned int* __restrict__ segHist){
  __shared__ unsigned int h[NBUCK];
  const int t = threadIdx.x;
  if (t < NBUCK) h[t] = 0;
  __syncthreads();
  const int n = blockIdx.z, hh = blockIdx.y, s = blockIdx.x;
  const unsigned char* cp = codes + ((size_t)n*NHASH + hh)*LL + (size_t)s*SEGL;
  for (int e=t; e<SEGL; e+=256) atomicAdd(&h[cp[e]], 1u);
  __syncthreads();
  if (t < NBUCK)
    segHist[(((size_t)(n*NHASH+hh))*NSEG + s)*NBUCK + t] = h[t];
}

__global__ __launch_bounds__(128) void k_scan(unsigned int* __restrict__ segHist){
  __shared__ unsigned int tot[NBUCK];
  __shared__ unsigned int base[NBUCK];
  const int b = threadIdx.x;
  const size_t off = (size_t)blockIdx.x * NSEG * NBUCK;
  unsigned int run = 0;
  for (int s=0;s<NSEG;s++){
    unsigned int v = segHist[off + (size_t)s*NBUCK + b];
    segHist[off + (size_t)s*NBUCK + b] = run;
    run += v;
  }
  tot[b] = run;
  __syncthreads();
  if (b==0){ unsigned int r=0; for (int i=0;i<NBUCK;i++){ base[i]=r; r+=tot[i]; } }
  __syncthreads();
  const unsigned int bb = base[b];
  for (int s=0;s<NSEG;s++) segHist[off + (size_t)s*NBUCK + b] += bb;
}

__global__ __launch_bounds__(256) void k_rank(const unsigned char* __restrict__ codes,
    const unsigned int* __restrict__ segHist, int* __restrict__ sortPos,
    int* __restrict__ srtIdx){
  __shared__ unsigned int cw[SEGL/4];
  __shared__ unsigned int sbase[NBUCK];
  const int t = threadIdx.x;
  const int n = blockIdx.z, hh = blockIdx.y, s = blockIdx.x;
  const size_t cb = ((size_t)n*NHASH + hh)*LL + (size_t)s*SEGL;
  const unsigned int* cp32 = (const unsigned int*)(codes + cb);
  for (int e=t; e<SEGL/4; e+=256) cw[e] = cp32[e];
  if (t < NBUCK)
    sbase[t] = segHist[(((size_t)(n*NHASH+hh))*NSEG + s)*NBUCK + t];
  __syncthreads();
  const size_t ob = ((size_t)n*NHASH + hh)*LL;
  for (int e=t; e<SEGL; e+=256){
    unsigned int c = (cw[e>>2] >> ((e&3)*8)) & 0xffu;
    unsigned int mul = c * 0x01010101u;
    int cnt = 0;
    const int nw = e >> 2;
    for (int wi=0; wi<nw; wi++){
      unsigned int v = cw[wi] ^ mul;
      unsigned int t1 = (v & 0x7f7f7f7fu) + 0x7f7f7f7fu;   // exact zero-byte detect
      unsigned int z = ~(t1 | v) & 0x80808080u;
      cnt += __popc(z);
    }
    unsigned int lastw = cw[nw];
    const int nbp = e & 3;
    for (int bp=0; bp<nbp; bp++)
      if (((lastw >> (bp*8)) & 0xffu) == c) cnt++;
    int pos = (int)sbase[c] + cnt;
    int l = s*SEGL + e;
    sortPos[ob + l] = pos;
    srtIdx[ob + pos] = l;
  }
}

// ---------------- attention: per (n,h,chunk), flash-style online softmax ----
__global__ __launch_bounds__(576) void k_attn(const float* __restrict__ xe,
    const float* __restrict__ ye, const int* __restrict__ srtIdx,
    unsigned short* __restrict__ retS, float* __restrict__ bscore){
  __shared__ float praw[CHK][JT+1];    // +1 pad: stride 49 (odd*... bank-safe)
  __shared__ float Kt[JT][17];         // pad 17: conflict-free writes
  __shared__ float Vt[JT][CV];
  __shared__ int   lkI[JT];
  __shared__ float scL[CHK], mL[CHK], lL[CHK];
  const int t = threadIdx.x;
  const int k = blockIdx.x, hh = blockIdx.y, n = blockIdx.z;
  const size_t sb = ((size_t)n*NHASH + hh)*LL;
  const int q = t % CHK, eg = t / CHK;   // 144 q x 4 output quarters
  const int pq = k*CHK + q;
  const int lq = srtIdx[sb + pq];
  float qv[16];
  {
    const float* xr = &xe[((size_t)n*LL + lq)*16];
    #pragma unroll
    for (int f=0;f<16;f++) qv[f] = xr[f];
  }
  float acc[16];
  #pragma unroll
  for (int i=0;i<16;i++) acc[i]=0.f;
  if (t < CHK){ mL[t] = -3.0e38f; lL[t] = 0.f; }
  for (int jt=0; jt<NT; jt++){
    __syncthreads();   // prev-tile PV done; mL/lL init visible on first iter
    const int kc = (jt<3) ? k : ((jt<6) ? ((k+NCHK-1)&(NCHK-1)) : ((k+1)&(NCHK-1)));
    const int jl0 = (jt%3)*JT;
    if (t < JT) lkI[t] = srtIdx[sb + (size_t)kc*CHK + jl0 + t];
    __syncthreads();
    if (t < JT){   // K rows, L2-normalized (norm clamped at 5e-5)
      const float* xr = &xe[((size_t)n*LL + lkI[t])*16];
      float tmp[16]; float ss = 0.f;
      #pragma unroll
      for (int f=0;f<16;f++){ float v = xr[f]; tmp[f]=v; ss = fmaf(v,v,ss); }
      float inv = 1.f / fmaxf(sqrtf(ss), 5e-5f);
      #pragma unroll
      for (int f=0;f<16;f++) Kt[t][f] = tmp[f]*inv;
    }
    for (int e=t; e<JT*CV; e+=576){
      int r = e >> 6, c = e & 63;
      Vt[r][c] = ye[((size_t)n*LL + lkI[r])*64 + c];
    }
    __syncthreads();
    #pragma unroll
    for (int jr=0; jr<12; jr++){
      const int j = eg*12 + jr;
      float s = 0.f;
      #pragma unroll
      for (int f=0;f<16;f++) s = fmaf(qv[f], Kt[j][f], s);
      praw[q][j] = s;
    }
    __syncthreads();
    if (t < CHK){
      float m0 = mL[t];
      float tm = -3.0e38f;
      for (int j=0;j<JT;j++) tm = fmaxf(tm, praw[t][j]);
      float mn = fmaxf(m0, tm);
      float sc = expf(m0 - mn);
      float sum = 0.f;
      for (int j=0;j<JT;j++){
        float pv = expf(praw[t][j] - mn);
        praw[t][j] = pv; sum += pv;
      }
      lL[t] = lL[t]*sc + sum;
      mL[t] = mn;
      scL[t] = sc;
    }
    __syncthreads();
    {
      const float s = scL[q];
      #pragma unroll
      for (int i=0;i<16;i++) acc[i] *= s;
      for (int j=0;j<JT;j++){
        const float pv = praw[q][j];
        const float4* vp = (const float4*)&Vt[j][eg*16];
        float vbuf[16];
        *(float4*)&vbuf[0]  = vp[0];
        *(float4*)&vbuf[4]  = vp[1];
        *(float4*)&vbuf[8]  = vp[2];
        *(float4*)&vbuf[12] = vp[3];
        #pragma unroll
        for (int i=0;i<16;i++) acc[i] = fmaf(pv, vbuf[i], acc[i]);
      }
    }
  }
  const float linv = 1.f / lL[q];
  unsigned int wds[8];
  #pragma unroll
  for (int i=0;i<8;i++){
    unsigned int lo = f2bf(acc[2*i]*linv);
    unsigned int hi = f2bf(acc[2*i+1]*linv);
    wds[i] = lo | (hi << 16);
  }
  uint4* op = (uint4*)&retS[(sb + pq)*64 + (size_t)eg*16];
  op[0] = make_uint4(wds[0],wds[1],wds[2],wds[3]);
  op[1] = make_uint4(wds[4],wds[5],wds[6],wds[7]);
  if (t < CHK) bscore[sb + pq] = mL[q] + logf(lL[q]);
}

// ---------------- unsort + hash-softmax combine + residual -------------------
__global__ __launch_bounds__(256) void k_combine(const unsigned short* __restrict__ retS,
    const float* __restrict__ bscore, const int* __restrict__ sortPos,
    const float* __restrict__ x2, float* __restrict__ out){
  const int idx = blockIdx.x*256 + threadIdx.x;
  if (idx >= NB*LL) return;
  const int l = idx % LL, n = idx / LL;
  float bs[NHASH]; int pp[NHASH];
  #pragma unroll
  for (int h=0;h<NHASH;h++){
    size_t sb = ((size_t)n*NHASH + h)*LL;
    int p = sortPos[sb + l];
    pp[h] = p; bs[h] = bscore[sb + p];
  }
  float m = fmaxf(fmaxf(bs[0],bs[1]), fmaxf(bs[2],bs[3]));
  float wsum = 0.f; float wv[NHASH];
  #pragma unroll
  for (int h=0;h<NHASH;h++){ wv[h] = expf(bs[h]-m); wsum += wv[h]; }
  const float winv = 1.f / wsum;
  float o[64];
  #pragma unroll
  for (int i=0;i<64;i++) o[i]=0.f;
  #pragma unroll
  for (int h=0;h<NHASH;h++){
    const float wh = wv[h]*winv;
    const uint4* rp = (const uint4*)&retS[(((size_t)n*NHASH + h)*LL + pp[h])*64];
    #pragma unroll
    for (int i2=0;i2<8;i2++){
      uint4 v = rp[i2];
      o[i2*8+0] = fmaf(wh, bfl(v.x), o[i2*8+0]);
      o[i2*8+1] = fmaf(wh, bfh(v.x), o[i2*8+1]);
      o[i2*8+2] = fmaf(wh, bfl(v.y), o[i2*8+2]);
      o[i2*8+3] = fmaf(wh, bfh(v.y), o[i2*8+3]);
      o[i2*8+4] = fmaf(wh, bfl(v.z), o[i2*8+4]);
      o[i2*8+5] = fmaf(wh, bfh(v.z), o[i2*8+5]);
      o[i2*8+6] = fmaf(wh, bfl(v.w), o[i2*8+6]);
      o[i2*8+7] = fmaf(wh, bfh(v.w), o[i2*8+7]);
    }
  }
  #pragma unroll
  for (int c=0;c<64;c++){
    size_t oi = ((size_t)n*64 + c)*LL + l;
    out[oi] = o[c] + x2[oi];
  }
}

extern "C" void kernel_launch(void* const* d_in, const int* in_sizes, int n_in,
                              void* d_out, int out_size, void* d_ws, size_t ws_size,
                              hipStream_t stream){
  const float* x   = (const float*)d_in[0];
  const float* w1  = (const float*)d_in[1];
  const float* b1  = (const float*)d_in[2];
  const float* w2  = (const float*)d_in[3];
  const float* b2  = (const float*)d_in[4];
  const float* wm  = (const float*)d_in[5];
  const float* bm  = (const float*)d_in[6];
  const float* wa  = (const float*)d_in[7];
  const float* ba  = (const float*)d_in[8];
  const float* rot = (const float*)d_in[9];
  float* outp = (float*)d_out;
  char* ws = (char*)d_ws;
  const size_t FM = (size_t)NB*CIN*HH*WW*sizeof(float);   // 18,874,368 B
  float* x0u = (float*)(ws + 0);
  float* y1  = (float*)(ws + FM);
  float* x2  = (float*)(ws + 2*FM);
  float* xe  = (float*)(ws + 3*FM);
  float* ye  = (float*)(ws + 3*FM + (size_t)NB*LL*CE*sizeof(float));
  char* p = ws + 3*FM + (size_t)NB*LL*CE*sizeof(float) + FM;
  unsigned char* codes = (unsigned char*)p; p += (size_t)NB*NHASH*LL;
  unsigned int* segHist = (unsigned int*)p; p += (size_t)NB*NHASH*NSEG*NBUCK*sizeof(unsigned int);
  int* sortPos = (int*)p; p += (size_t)NB*NHASH*LL*sizeof(int);
  int* srtIdx  = (int*)p; p += (size_t)NB*NHASH*LL*sizeof(int);
  float* bscore = (float*)p; p += (size_t)NB*NHASH*LL*sizeof(float);
  unsigned short* retS = (unsigned short*)ws;  // reuse x0u+y1 (exactly 2*FM)
  if (ws_size < (size_t)(p - ws)) return;      // ~84.3 MB required

  k_upsample<<<dim3((NB*CIN*HH*WW+255)/256), dim3(256), 0, stream>>>(x, x0u);
  k_conv3<64,true,false><<<dim3(WW/32, HH/16, NB*4), dim3(128), 0, stream>>>(x0u, w1, b1, y1);
  k_conv3<64,true,false><<<dim3(WW/32, HH/16, NB*4), dim3(128), 0, stream>>>(y1, w2, b2, x2);
  k_conv3<16,false,true><<<dim3(WW/32, HH/16, NB), dim3(128), 0, stream>>>(x2, wm, bm, xe);
  k_conv1x1<<<dim3(LL/64, NB), dim3(256), 0, stream>>>(x2, wa, ba, ye);
  k_codes<<<dim3(LL/128, NB), dim3(128), 0, stream>>>(xe, rot, codes);
  k_hist<<<dim3(NSEG, NHASH, NB), dim3(256), 0, stream>>>(codes, segHist);
  k_scan<<<dim3(NB*NHASH), dim3(128), 0, stream>>>(segHist);
  k_rank<<<dim3(NSEG, NHASH, NB), dim3(256), 0, stream>>>(codes, segHist, sortPos, srtIdx);
  k_attn<<<dim3(NCHK, NHASH, NB), dim3(576), 0, stream>>>(xe, ye, srtIdx, retS, bscore);
  k_combine<<<dim3((NB*LL+255)/256), dim3(256), 0, stream>>>(retS, bscore, sortPos, x2, outp);
}

// Round 2
// 867.636 us; speedup vs baseline: 1.8609x; 1.8609x over previous
//
#include <hip/hip_runtime.h>
#include <math.h>

#define NB 2
#define CIN 64
#define H0 96
#define W0 96
#define HH 192
#define WW 192
#define LL (HH*WW)        // 36864
#define NHASH 4
#define CHK 144
#define NCHK 256          // LL/CHK
#define CE 16
#define CV 64
#define NBUCK 128
#define SEGL 576
#define NSEG 64           // LL/SEGL

// ---- attention LDS layout (bytes) ----
#define K_ROWB   80              // [Kh f0..15 | Kl f0..15 | 8B pad] per j-row
#define V_ROWB   912             // 456 bf16 cols (432 keys + 16 zero-pad + 8 pad)
#define AT_KOFF  0               // 432*80    = 34560
#define AT_VOFF  34560           // 64*912    = 58368
#define AT_POFF  92928           // 9*16*80   = 11520
#define AT_IOFF  104448          // 432*4     = 1728
#define AT_LDS   106176

typedef __attribute__((ext_vector_type(8))) short short8_t;
typedef __attribute__((ext_vector_type(4))) float f32x4;
union FragU { unsigned int u[4]; int4 i; short8_t s; };

__device__ __forceinline__ unsigned int cvtpk_bf16(float a, float b){
  unsigned int r;
  asm("v_cvt_pk_bf16_f32 %0, %1, %2" : "=v"(r) : "v"(a), "v"(b));
  return r;
}
__device__ __forceinline__ float bfl(unsigned int u){ return __uint_as_float(u << 16); }
__device__ __forceinline__ float bfh(unsigned int u){ return __uint_as_float(u & 0xffff0000u); }

// ---------------- bicubic 2x upsample (separable, edge pad) ----------------
__global__ __launch_bounds__(256) void k_upsample(const float* __restrict__ x,
                                                  float* __restrict__ out){
  int idx = blockIdx.x*256 + threadIdx.x;
  if (idx >= NB*CIN*HH*WW) return;
  int ox = idx % WW; int t2 = idx / WW;
  int oy = t2 % HH;  t2 /= HH;           // t2 = n*CIN + c
  int i = oy >> 1, a = oy & 1;
  int j = ox >> 1, b = ox & 1;
  const float e0=-0.03515625f, e1=0.26171875f, e2=0.87890625f, e3=-0.10546875f;
  float wy[4], wx[4]; int ty[4], tx[4];
  if (a){ wy[0]=e3; wy[1]=e2; wy[2]=e1; wy[3]=e0; } else { wy[0]=e0; wy[1]=e1; wy[2]=e2; wy[3]=e3; }
  if (b){ wx[0]=e3; wx[1]=e2; wx[2]=e1; wx[3]=e0; } else { wx[0]=e0; wx[1]=e1; wx[2]=e2; wx[3]=e3; }
  int offy = a ? -1 : -2, offx = b ? -1 : -2;
  #pragma unroll
  for (int k=0;k<4;k++){
    int t = i + offy + k; ty[k] = t<0?0:(t>H0-1?H0-1:t);
    int s = j + offx + k; tx[k] = s<0?0:(s>W0-1?W0-1:s);
  }
  const float* xp = x + (size_t)t2*H0*W0;
  float s = 0.f;
  #pragma unroll
  for (int ky=0;ky<4;ky++){
    const float* row = xp + ty[ky]*W0;
    float rs = 0.f;
    rs = fmaf(wx[0], row[tx[0]], rs);
    rs = fmaf(wx[1], row[tx[1]], rs);
    rs = fmaf(wx[2], row[tx[2]], rs);
    rs = fmaf(wx[3], row[tx[3]], rs);
    s = fmaf(wy[ky], rs, s);
  }
  out[idx] = s;
}

// ---------------- direct 3x3 conv, pad 1 -----------------------------------
template<int CO_TOT, bool RELU, bool OUT_NLC>
__global__ __launch_bounds__(128) void k_conv3(const float* __restrict__ in,
    const float* __restrict__ wgt, const float* __restrict__ bias,
    float* __restrict__ out){
  __shared__ float in_t[4][18][36];
  __shared__ float wt[4][9][16];
  const int t = threadIdx.x;
  const int bx = blockIdx.x, by = blockIdx.y, bz = blockIdx.z;
  constexpr int NCOG = CO_TOT/16;
  const int cog = bz % NCOG;
  const int n = bz / NCOG;
  const int co0 = cog*16;
  const int tx = t & 15, ty = t >> 4;
  const int px0 = tx*2, py0 = ty*2;
  const int gx0 = bx*32, gy0 = by*16;
  float acc[16][4];
  #pragma unroll
  for (int c=0;c<16;c++){ acc[c][0]=0.f; acc[c][1]=0.f; acc[c][2]=0.f; acc[c][3]=0.f; }
  for (int ci0=0; ci0<CIN; ci0+=4){
    for (int e=t; e<4*18*34; e+=128){
      int ci = e/(18*34); int rem = e - ci*(18*34);
      int r = rem/34; int cx = rem - r*34;
      int gy = gy0 + r - 1, gx = gx0 + cx - 1;
      float v = 0.f;
      if (gy>=0 && gy<HH && gx>=0 && gx<WW)
        v = in[(((size_t)n*CIN + ci0+ci)*HH + gy)*WW + gx];
      in_t[ci][r][cx] = v;
    }
    for (int e=t; e<4*9*16; e+=128){
      int ci = e/144; int rem = e - ci*144;
      int kk = rem >> 4; int co = rem & 15;
      wt[ci][kk][co] = wgt[(((size_t)(co0+co))*CIN + ci0+ci)*9 + kk];
    }
    __syncthreads();
    #pragma unroll
    for (int ci=0; ci<4; ci++){
      #pragma unroll
      for (int ky=0; ky<3; ky++){
        float v0=in_t[ci][py0+ky][px0+0], v1=in_t[ci][py0+ky][px0+1],
              v2=in_t[ci][py0+ky][px0+2], v3=in_t[ci][py0+ky][px0+3];
        float u0=in_t[ci][py0+ky+1][px0+0], u1=in_t[ci][py0+ky+1][px0+1],
              u2=in_t[ci][py0+ky+1][px0+2], u3=in_t[ci][py0+ky+1][px0+3];
        #pragma unroll
        for (int kx=0; kx<3; kx++){
          float a0 = (kx==0)?v0:((kx==1)?v1:v2);
          float a1 = (kx==0)?v1:((kx==1)?v2:v3);
          float b0 = (kx==0)?u0:((kx==1)?u1:u2);
          float b1 = (kx==0)?u1:((kx==1)?u2:u3);
          #pragma unroll
          for (int c=0;c<16;c++){
            float wv = wt[ci][ky*3+kx][c];
            acc[c][0] = fmaf(a0, wv, acc[c][0]);
            acc[c][1] = fmaf(a1, wv, acc[c][1]);
            acc[c][2] = fmaf(b0, wv, acc[c][2]);
            acc[c][3] = fmaf(b1, wv, acc[c][3]);
          }
        }
      }
    }
    __syncthreads();
  }
  #pragma unroll
  for (int c=0;c<16;c++){
    float bv = bias[co0+c];
    #pragma unroll
    for (int p=0;p<4;p++){
      int iy = p>>1, ix = p&1;
      float vv = acc[c][p] + bv;
      if (RELU) vv = fmaxf(vv, 0.f);
      int yy = gy0+py0+iy, xx = gx0+px0+ix;
      if (OUT_NLC)
        out[((size_t)n*LL + yy*WW+xx)*16 + c] = vv;
      else
        out[(((size_t)n*CO_TOT + co0+c)*HH + yy)*WW + xx] = vv;
    }
  }
}

// ---------------- 1x1 conv (ye), output [N][L][64] --------------------------
__global__ __launch_bounds__(256) void k_conv1x1(const float* __restrict__ x2,
    const float* __restrict__ wa, const float* __restrict__ ba,
    float* __restrict__ ye){
  __shared__ float xs[64][64];
  __shared__ float wts[64][64];
  const int t = threadIdx.x;
  const int n = blockIdx.y;
  const int l0 = blockIdx.x*64;
  for (int e=t; e<4096; e+=256){
    int ci = e >> 6, l = e & 63;
    xs[ci][l]  = x2[((size_t)n*CIN+ci)*LL + l0 + l];
    wts[ci][l] = wa[(size_t)l*64 + ci];          // wts[ci][co]
  }
  __syncthreads();
  const int l = t & 63, cq = t >> 6;
  float acc[16];
  #pragma unroll
  for (int i=0;i<16;i++) acc[i] = ba[cq*16+i];
  for (int ci=0; ci<64; ci++){
    float xv = xs[ci][l];
    #pragma unroll
    for (int i=0;i<16;i++) acc[i] = fmaf(xv, wts[ci][cq*16+i], acc[i]);
  }
  float* op = &ye[((size_t)n*LL + l0 + l)*64 + cq*16];
  #pragma unroll
  for (int i=0;i<16;i++) op[i] = acc[i];
}

// ---------------- LSH codes: argmax over [rot ; -rot] ------------------------
__global__ __launch_bounds__(128) void k_codes(const float* __restrict__ xe,
    const float* __restrict__ rot, unsigned char* __restrict__ codes){
  __shared__ float rs[NHASH][64][16];
  const int t = threadIdx.x;
  for (int e=t; e<4096; e+=128){
    int f = e >> 8; int rem = e & 255;
    int h = rem >> 6; int i = rem & 63;
    rs[h][i][f] = rot[((size_t)f*NHASH + h)*64 + i];
  }
  __syncthreads();
  const int n = blockIdx.y;
  const int l = blockIdx.x*128 + t;
  float q[16];
  const float* xr = &xe[((size_t)n*LL + l)*16];
  #pragma unroll
  for (int f=0;f<16;f++) q[f] = xr[f];
  #pragma unroll
  for (int h=0;h<NHASH;h++){
    float bp = -3.0e38f, bn = -3.0e38f; int ap=0, an=0;
    for (int i=0;i<64;i++){
      float s = 0.f;
      #pragma unroll
      for (int f=0;f<16;f++) s = fmaf(q[f], rs[h][i][f], s);
      if (s > bp){ bp = s; ap = i; }
      if (-s > bn){ bn = -s; an = i; }
    }
    int code = (bp >= bn) ? ap : (64 + an);   // first-index tie rule of argmax
    codes[((size_t)n*NHASH + h)*LL + l] = (unsigned char)code;
  }
}

// ---------------- stable counting sort: hist / scan / rank+scatter ----------
__global__ __launch_bounds__(256) void k_hist(const unsigned char* __restrict__ codes,
    unsigned int* __restrict__ segHist){
  __shared__ unsigned int h[NBUCK];
  const int t = threadIdx.x;
  if (t < NBUCK) h[t] = 0;
  __syncthreads();
  const int n = blockIdx.z, hh = blockIdx.y, s = blockIdx.x;
  const unsigned char* cp = codes + ((size_t)n*NHASH + hh)*LL + (size_t)s*SEGL;
  for (int e=t; e<SEGL; e+=256) atomicAdd(&h[cp[e]], 1u);
  __syncthreads();
  if (t < NBUCK)
    segHist[(((size_t)(n*NHASH+hh))*NSEG + s)*NBUCK + t] = h[t];
}

__global__ __launch_bounds__(128) void k_scan(unsigned int* __restrict__ segHist){
  __shared__ unsigned int tot[NBUCK];
  __shared__ unsigned int base[NBUCK];
  const int b = threadIdx.x;
  const size_t off = (size_t)blockIdx.x * NSEG * NBUCK;
  unsigned int run = 0;
  for (int s=0;s<NSEG;s++){
    unsigned int v = segHist[off + (size_t)s*NBUCK + b];
    segHist[off + (size_t)s*NBUCK + b] = run;
    run += v;
  }
  tot[b] = run;
  __syncthreads();
  if (b==0){ unsigned int r=0; for (int i=0;i<NBUCK;i++){ base[i]=r; r+=tot[i]; } }
  __syncthreads();
  const unsigned int bb = base[b];
  for (int s=0;s<NSEG;s++) segHist[off + (size_t)s*NBUCK + b] += bb;
}

__global__ __launch_bounds__(256) void k_rank(const unsigned char* __restrict__ codes,
    const unsigned int* __restrict__ segHist, int* __restrict__ sortPos,
    int* __restrict__ srtIdx){
  __shared__ unsigned int cw[SEGL/4];
  __shared__ unsigned int sbase[NBUCK];
  const int t = threadIdx.x;
  const int n = blockIdx.z, hh = blockIdx.y, s = blockIdx.x;
  const size_t cb = ((size_t)n*NHASH + hh)*LL + (size_t)s*SEGL;
  const unsigned int* cp32 = (const unsigned int*)(codes + cb);
  for (int e=t; e<SEGL/4; e+=256) cw[e] = cp32[e];
  if (t < NBUCK)
    sbase[t] = segHist[(((size_t)(n*NHASH+hh))*NSEG + s)*NBUCK + t];
  __syncthreads();
  const size_t ob = ((size_t)n*NHASH + hh)*LL;
  for (int e=t; e<SEGL; e+=256){
    unsigned int c = (cw[e>>2] >> ((e&3)*8)) & 0xffu;
    unsigned int mul = c * 0x01010101u;
    int cnt = 0;
    const int nw = e >> 2;
    for (int wi=0; wi<nw; wi++){
      unsigned int v = cw[wi] ^ mul;
      unsigned int t1 = (v & 0x7f7f7f7fu) + 0x7f7f7f7fu;   // exact zero-byte detect
      unsigned int z = ~(t1 | v) & 0x80808080u;
      cnt += __popc(z);
    }
    unsigned int lastw = cw[nw];
    const int nbp = e & 3;
    for (int bp=0; bp<nbp; bp++)
      if (((lastw >> (bp*8)) & 0xffu) == c) cnt++;
    int pos = (int)sbase[c] + cnt;
    int l = s*SEGL + e;
    sortPos[ob + l] = pos;
    srtIdx[ob + pos] = l;
  }
}

// ---------------- attention: MFMA (bf16x2-split QK, bf16 PV) ----------------
// block = 576 thr = 9 waves; wave w owns q-tile w (16 q rows of the 144-chunk).
// S^T = K*Q^T (16x16x32 mfma): C layout col=lane&15=q, row=j (verified m89);
// softmax per q-column => in-thread + shfl_xor(16,32) reduce.
// P^T written to per-wave LDS, re-read as B-frags for O^T = V^T * P^T.
__global__ __launch_bounds__(576) void k_attn(const float* __restrict__ xe,
    const float* __restrict__ ye, const int* __restrict__ srtIdx,
    unsigned short* __restrict__ retS, float* __restrict__ bscore){
  extern __shared__ char smem[];
  unsigned short* Kq = (unsigned short*)(smem + AT_KOFF);  // [432][40] bf16
  char* Vt  = smem + AT_VOFF;                              // [64][456] bf16
  char* Pst = smem + AT_POFF;                              // [9][16][40] bf16
  int* lkI  = (int*)(smem + AT_IOFF);                      // [432]

  const int t = threadIdx.x;
  const int k = blockIdx.x, hh = blockIdx.y, n = blockIdx.z;
  const size_t sb = ((size_t)n*NHASH + hh)*LL;
  const int l = t & 63, w = t >> 6;
  const int lq16 = l & 15, g = l >> 4;

  // ---- phase 0: gather indices + stage normalized split-K ----
  if (t < 432){
    const int c3 = t / CHK, jl = t - c3*CHK;
    const int kc = (c3==0) ? k : ((c3==1) ? ((k+NCHK-1)&(NCHK-1)) : ((k+1)&(NCHK-1)));
    const int lk = srtIdx[sb + (size_t)kc*CHK + jl];
    lkI[t] = lk;
    const float4* xr = (const float4*)&xe[((size_t)n*LL + lk)*16];
    float4 v0 = xr[0], v1 = xr[1], v2 = xr[2], v3 = xr[3];
    float f[16] = {v0.x,v0.y,v0.z,v0.w, v1.x,v1.y,v1.z,v1.w,
                   v2.x,v2.y,v2.z,v2.w, v3.x,v3.y,v3.z,v3.w};
    float ss = 0.f;
    #pragma unroll
    for (int i=0;i<16;i++) ss = fmaf(f[i], f[i], ss);
    const float inv = 1.f / fmaxf(sqrtf(ss), 5e-5f);
    #pragma unroll
    for (int i=0;i<16;i++) f[i] *= inv;
    unsigned int kh[8], klo[8];
    #pragma unroll
    for (int i=0;i<8;i++) kh[i] = cvtpk_bf16(f[2*i], f[2*i+1]);
    #pragma unroll
    for (int i=0;i<8;i++)
      klo[i] = cvtpk_bf16(f[2*i] - bfl(kh[i]), f[2*i+1] - bfh(kh[i]));
    int4* kr = (int4*)((char*)Kq + t*K_ROWB);
    kr[0] = make_int4((int)kh[0],(int)kh[1],(int)kh[2],(int)kh[3]);
    kr[1] = make_int4((int)kh[4],(int)kh[5],(int)kh[6],(int)kh[7]);
    kr[2] = make_int4((int)klo[0],(int)klo[1],(int)klo[2],(int)klo[3]);
    kr[3] = make_int4((int)klo[4],(int)klo[5],(int)klo[6],(int)klo[7]);
  }
  // zero phantom V columns j=432..447
  if (t < 512){
    int c = t >> 3, jp = t & 7;
    *(unsigned int*)(Vt + c*V_ROWB + 864 + jp*4) = 0u;
  }
  __syncthreads();

  // ---- phase 1: stage V^T (bf16, [c][j]) + build Q fragments ----
  #pragma unroll 4
  for (int it=0; it<24; ++it){
    const int e = t + it*576;
    const int jp = e >> 6, c = e & 63;
    const float a = ye[((size_t)n*LL + lkI[2*jp  ])*64 + c];
    const float b = ye[((size_t)n*LL + lkI[2*jp+1])*64 + c];
    *(unsigned int*)(Vt + c*V_ROWB + jp*4) = cvtpk_bf16(a, b);
  }
  const int qg = w*16 + lq16;
  const int pq = k*CHK + qg;
  FragU b1, b2;
  {
    const int lq = lkI[qg];
    const float4* qp = (const float4*)&xe[((size_t)n*LL + lq)*16 + (size_t)(g&1)*8];
    float4 qa = qp[0], qb = qp[1];
    b1.u[0] = cvtpk_bf16(qa.x, qa.y); b1.u[1] = cvtpk_bf16(qa.z, qa.w);
    b1.u[2] = cvtpk_bf16(qb.x, qb.y); b1.u[3] = cvtpk_bf16(qb.z, qb.w);
    if (g < 2){
      b2.u[0] = cvtpk_bf16(qa.x - bfl(b1.u[0]), qa.y - bfh(b1.u[0]));
      b2.u[1] = cvtpk_bf16(qa.z - bfl(b1.u[1]), qa.w - bfh(b1.u[1]));
      b2.u[2] = cvtpk_bf16(qb.x - bfl(b1.u[2]), qb.y - bfh(b1.u[2]));
      b2.u[3] = cvtpk_bf16(qb.z - bfl(b1.u[3]), qb.w - bfh(b1.u[3]));
    } else {
      b2.u[0]=0u; b2.u[1]=0u; b2.u[2]=0u; b2.u[3]=0u;
    }
  }
  __syncthreads();

  // ---- pass 1: exact per-q max over all 432 keys ----
  const char* Kb = (const char*)Kq + lq16*K_ROWB + g*16;
  float m = -3.0e38f;
  for (int t27=0; t27<27; ++t27){
    FragU a; a.i = *(const int4*)(Kb + (size_t)t27*16*K_ROWB);
    f32x4 C = {0.f,0.f,0.f,0.f};
    C = __builtin_amdgcn_mfma_f32_16x16x32_bf16(a.s, b2.s, C, 0, 0, 0);
    C = __builtin_amdgcn_mfma_f32_16x16x32_bf16(a.s, b1.s, C, 0, 0, 0);
    m = fmaxf(m, fmaxf(fmaxf(C[0],C[1]), fmaxf(C[2],C[3])));
  }
  m = fmaxf(m, __shfl_xor(m, 16));
  m = fmaxf(m, __shfl_xor(m, 32));

  // ---- pass 2: recompute S, P=exp(S-m), accumulate sum and O^T = V^T P^T ----
  float sum = 0.f;
  f32x4 O0 = {0.f,0.f,0.f,0.f}, O1 = O0, O2 = O0, O3 = O0;
  char* Pw = Pst + w*1280;
  for (int u=0; u<14; ++u){
    #pragma unroll
    for (int sub=0; sub<2; ++sub){
      const int t27 = u*2 + sub;
      uint2 pw;
      if (t27 < 27){
        FragU a; a.i = *(const int4*)(Kb + (size_t)t27*16*K_ROWB);
        f32x4 C = {0.f,0.f,0.f,0.f};
        C = __builtin_amdgcn_mfma_f32_16x16x32_bf16(a.s, b2.s, C, 0, 0, 0);
        C = __builtin_amdgcn_mfma_f32_16x16x32_bf16(a.s, b1.s, C, 0, 0, 0);
        const float p0 = __expf(C[0]-m), p1 = __expf(C[1]-m);
        const float p2 = __expf(C[2]-m), p3 = __expf(C[3]-m);
        sum += (p0+p1) + (p2+p3);
        pw = make_uint2(cvtpk_bf16(p0,p1), cvtpk_bf16(p2,p3));
      } else {
        pw = make_uint2(0u, 0u);
      }
      *(uint2*)(Pw + lq16*K_ROWB + sub*32 + g*8) = pw;
    }
    asm volatile("s_waitcnt lgkmcnt(0)" ::: "memory");
    __builtin_amdgcn_sched_barrier(0);
    FragU bp; bp.i = *(const int4*)(Pw + lq16*K_ROWB + g*16);
    const char* Vb = Vt + lq16*V_ROWB + u*64 + g*16;
    FragU av;
    av.i = *(const int4*)(Vb);            O0 = __builtin_amdgcn_mfma_f32_16x16x32_bf16(av.s, bp.s, O0, 0,0,0);
    av.i = *(const int4*)(Vb + 16*V_ROWB); O1 = __builtin_amdgcn_mfma_f32_16x16x32_bf16(av.s, bp.s, O1, 0,0,0);
    av.i = *(const int4*)(Vb + 32*V_ROWB); O2 = __builtin_amdgcn_mfma_f32_16x16x32_bf16(av.s, bp.s, O2, 0,0,0);
    av.i = *(const int4*)(Vb + 48*V_ROWB); O3 = __builtin_amdgcn_mfma_f32_16x16x32_bf16(av.s, bp.s, O3, 0,0,0);
  }
  sum += __shfl_xor(sum, 16);
  sum += __shfl_xor(sum, 32);
  const float linv = 1.f / sum;

  unsigned short* op = &retS[(sb + pq)*64];
  {
    uint2 s0 = make_uint2(cvtpk_bf16(O0[0]*linv, O0[1]*linv), cvtpk_bf16(O0[2]*linv, O0[3]*linv));
    uint2 s1 = make_uint2(cvtpk_bf16(O1[0]*linv, O1[1]*linv), cvtpk_bf16(O1[2]*linv, O1[3]*linv));
    uint2 s2 = make_uint2(cvtpk_bf16(O2[0]*linv, O2[1]*linv), cvtpk_bf16(O2[2]*linv, O2[3]*linv));
    uint2 s3 = make_uint2(cvtpk_bf16(O3[0]*linv, O3[1]*linv), cvtpk_bf16(O3[2]*linv, O3[3]*linv));
    *(uint2*)(op +  0 + g*4) = s0;
    *(uint2*)(op + 16 + g*4) = s1;
    *(uint2*)(op + 32 + g*4) = s2;
    *(uint2*)(op + 48 + g*4) = s3;
  }
  if (g == 0) bscore[sb + pq] = m + logf(sum);
}

// ---------------- unsort + hash-softmax combine + residual -------------------
__global__ __launch_bounds__(256) void k_combine(const unsigned short* __restrict__ retS,
    const float* __restrict__ bscore, const int* __restrict__ sortPos,
    const float* __restrict__ x2, float* __restrict__ out){
  const int idx = blockIdx.x*256 + threadIdx.x;
  if (idx >= NB*LL) return;
  const int l = idx % LL, n = idx / LL;
  float bs[NHASH]; int pp[NHASH];
  #pragma unroll
  for (int h=0;h<NHASH;h++){
    size_t sb = ((size_t)n*NHASH + h)*LL;
    int p = sortPos[sb + l];
    pp[h] = p; bs[h] = bscore[sb + p];
  }
  float m = fmaxf(fmaxf(bs[0],bs[1]), fmaxf(bs[2],bs[3]));
  float wsum = 0.f; float wv[NHASH];
  #pragma unroll
  for (int h=0;h<NHASH;h++){ wv[h] = expf(bs[h]-m); wsum += wv[h]; }
  const float winv = 1.f / wsum;
  float o[64];
  #pragma unroll
  for (int i=0;i<64;i++) o[i]=0.f;
  #pragma unroll
  for (int h=0;h<NHASH;h++){
    const float wh = wv[h]*winv;
    const uint4* rp = (const uint4*)&retS[(((size_t)n*NHASH + h)*LL + pp[h])*64];
    #pragma unroll
    for (int i2=0;i2<8;i2++){
      uint4 v = rp[i2];
      o[i2*8+0] = fmaf(wh, bfl(v.x), o[i2*8+0]);
      o[i2*8+1] = fmaf(wh, bfh(v.x), o[i2*8+1]);
      o[i2*8+2] = fmaf(wh, bfl(v.y), o[i2*8+2]);
      o[i2*8+3] = fmaf(wh, bfh(v.y), o[i2*8+3]);
      o[i2*8+4] = fmaf(wh, bfl(v.z), o[i2*8+4]);
      o[i2*8+5] = fmaf(wh, bfh(v.z), o[i2*8+5]);
      o[i2*8+6] = fmaf(wh, bfl(v.w), o[i2*8+6]);
      o[i2*8+7] = fmaf(wh, bfh(v.w), o[i2*8+7]);
    }
  }
  #pragma unroll
  for (int c=0;c<64;c++){
    size_t oi = ((size_t)n*64 + c)*LL + l;
    out[oi] = o[c] + x2[oi];
  }
}

extern "C" void kernel_launch(void* const* d_in, const int* in_sizes, int n_in,
                              void* d_out, int out_size, void* d_ws, size_t ws_size,
                              hipStream_t stream){
  const float* x   = (const float*)d_in[0];
  const float* w1  = (const float*)d_in[1];
  const float* b1  = (const float*)d_in[2];
  const float* w2  = (const float*)d_in[3];
  const float* b2  = (const float*)d_in[4];
  const float* wm  = (const float*)d_in[5];
  const float* bm  = (const float*)d_in[6];
  const float* wa  = (const float*)d_in[7];
  const float* ba  = (const float*)d_in[8];
  const float* rot = (const float*)d_in[9];
  float* outp = (float*)d_out;
  char* ws = (char*)d_ws;
  const size_t FM = (size_t)NB*CIN*HH*WW*sizeof(float);   // 18,874,368 B
  float* x0u = (float*)(ws + 0);
  float* y1  = (float*)(ws + FM);
  float* x2  = (float*)(ws + 2*FM);
  float* xe  = (float*)(ws + 3*FM);
  float* ye  = (float*)(ws + 3*FM + (size_t)NB*LL*CE*sizeof(float));
  char* p = ws + 3*FM + (size_t)NB*LL*CE*sizeof(float) + FM;
  unsigned char* codes = (unsigned char*)p; p += (size_t)NB*NHASH*LL;
  unsigned int* segHist = (unsigned int*)p; p += (size_t)NB*NHASH*NSEG*NBUCK*sizeof(unsigned int);
  int* sortPos = (int*)p; p += (size_t)NB*NHASH*LL*sizeof(int);
  int* srtIdx  = (int*)p; p += (size_t)NB*NHASH*LL*sizeof(int);
  float* bscore = (float*)p; p += (size_t)NB*NHASH*LL*sizeof(float);
  unsigned short* retS = (unsigned short*)ws;  // reuse x0u+y1 (exactly 2*FM)
  if (ws_size < (size_t)(p - ws)) return;      // ~84.3 MB required

  hipFuncSetAttribute((const void*)k_attn,
                      hipFuncAttributeMaxDynamicSharedMemorySize, AT_LDS);

  k_upsample<<<dim3((NB*CIN*HH*WW+255)/256), dim3(256), 0, stream>>>(x, x0u);
  k_conv3<64,true,false><<<dim3(WW/32, HH/16, NB*4), dim3(128), 0, stream>>>(x0u, w1, b1, y1);
  k_conv3<64,true,false><<<dim3(WW/32, HH/16, NB*4), dim3(128), 0, stream>>>(y1, w2, b2, x2);
  k_conv3<16,false,true><<<dim3(WW/32, HH/16, NB), dim3(128), 0, stream>>>(x2, wm, bm, xe);
  k_conv1x1<<<dim3(LL/64, NB), dim3(256), 0, stream>>>(x2, wa, ba, ye);
  k_codes<<<dim3(LL/128, NB), dim3(128), 0, stream>>>(xe, rot, codes);
  k_hist<<<dim3(NSEG, NHASH, NB), dim3(256), 0, stream>>>(codes, segHist);
  k_scan<<<dim3(NB*NHASH), dim3(128), 0, stream>>>(segHist);
  k_rank<<<dim3(NSEG, NHASH, NB), dim3(256), 0, stream>>>(codes, segHist, sortPos, srtIdx);
  k_attn<<<dim3(NCHK, NHASH, NB), dim3(576), AT_LDS, stream>>>(xe, ye, srtIdx, retS, bscore);
  k_combine<<<dim3((NB*LL+255)/256), dim3(256), 0, stream>>>(retS, bscore, sortPos, x2, outp);
}

// Round 3
// 643.559 us; speedup vs baseline: 2.5089x; 1.3482x over previous
//
#include <hip/hip_runtime.h>
#include <math.h>

#define NB 2
#define CIN 64
#define H0 96
#define W0 96
#define HH 192
#define WW 192
#define LL (HH*WW)        // 36864
#define NHASH 4
#define CHK 144
#define NCHK 256          // LL/CHK
#define CE 16
#define CV 64
#define NBUCK 128
#define SEGL 576
#define NSEG 64           // LL/SEGL

// ---- attention LDS layout (bytes) ----
#define K_ROWB   80              // [Kh f0..15 | Kl f0..15 | 8B pad] per j-row
#define V_ROWB   912             // 456 bf16 cols (432 keys + 16 zero-pad + 8 pad)
#define AT_KOFF  0               // 432*80    = 34560
#define AT_VOFF  34560           // 64*912    = 58368
#define AT_POFF  92928           // 9*16*80   = 11520
#define AT_IOFF  104448          // 432*4     = 1728
#define AT_LDS   106176

typedef __attribute__((ext_vector_type(8))) short short8_t;
typedef __attribute__((ext_vector_type(4))) float f32x4;
union FragU { unsigned int u[4]; int4 i; short8_t s; };

__device__ __forceinline__ unsigned int cvtpk_bf16(float a, float b){
  unsigned int r;
  asm("v_cvt_pk_bf16_f32 %0, %1, %2" : "=v"(r) : "v"(a), "v"(b));
  return r;
}
__device__ __forceinline__ float bfl(unsigned int u){ return __uint_as_float(u << 16); }
__device__ __forceinline__ float bfh(unsigned int u){ return __uint_as_float(u & 0xffff0000u); }

// ---------------- bicubic 2x upsample (separable, edge pad) ----------------
__global__ __launch_bounds__(256) void k_upsample(const float* __restrict__ x,
                                                  float* __restrict__ out){
  int idx = blockIdx.x*256 + threadIdx.x;
  if (idx >= NB*CIN*HH*WW) return;
  int ox = idx % WW; int t2 = idx / WW;
  int oy = t2 % HH;  t2 /= HH;           // t2 = n*CIN + c
  int i = oy >> 1, a = oy & 1;
  int j = ox >> 1, b = ox & 1;
  const float e0=-0.03515625f, e1=0.26171875f, e2=0.87890625f, e3=-0.10546875f;
  float wy[4], wx[4]; int ty[4], tx[4];
  if (a){ wy[0]=e3; wy[1]=e2; wy[2]=e1; wy[3]=e0; } else { wy[0]=e0; wy[1]=e1; wy[2]=e2; wy[3]=e3; }
  if (b){ wx[0]=e3; wx[1]=e2; wx[2]=e1; wx[3]=e0; } else { wx[0]=e0; wx[1]=e1; wx[2]=e2; wx[3]=e3; }
  int offy = a ? -1 : -2, offx = b ? -1 : -2;
  #pragma unroll
  for (int k=0;k<4;k++){
    int t = i + offy + k; ty[k] = t<0?0:(t>H0-1?H0-1:t);
    int s = j + offx + k; tx[k] = s<0?0:(s>W0-1?W0-1:s);
  }
  const float* xp = x + (size_t)t2*H0*W0;
  float s = 0.f;
  #pragma unroll
  for (int ky=0;ky<4;ky++){
    const float* row = xp + ty[ky]*W0;
    float rs = 0.f;
    rs = fmaf(wx[0], row[tx[0]], rs);
    rs = fmaf(wx[1], row[tx[1]], rs);
    rs = fmaf(wx[2], row[tx[2]], rs);
    rs = fmaf(wx[3], row[tx[3]], rs);
    s = fmaf(wy[ky], rs, s);
  }
  out[idx] = s;
}

// ---------------- direct 3x3 conv v2, pad 1 ---------------------------------
// 512-thread blocks; thread = CO_T(2) out-ch x PX px; weights via float2
// broadcast reads, input rows via ds_read_b128 sliding window.
template<int CO_TOT, int CO_G, int PX, int TW, int TH, bool RELU, bool OUT_NLC>
__global__ __launch_bounds__(512) void k_conv3v2(const float* __restrict__ in,
    const float* __restrict__ wgt, const float* __restrict__ bias,
    float* __restrict__ out){
  constexpr int CO_T = 2;
  constexpr int CI_C = 8;
  constexpr int NROWG = TW/PX;
  constexpr int NPXG  = NROWG*TH;
  constexpr int NCOG_T = CO_G/CO_T;
  constexpr int NTHR = NPXG*NCOG_T;          // 512
  constexpr int TWP  = TW+2;
  constexpr int TWPR = (TWP+3)&~3;
  constexpr int NZCO = CO_TOT/CO_G;
  __shared__ float in_t[CI_C][TH+2][TWPR];
  __shared__ float wt[CI_C][9][CO_G];
  const int t = threadIdx.x;
  const int bx = blockIdx.x, by = blockIdx.y, bz = blockIdx.z;
  const int n = bz / NZCO;
  const int co0 = (bz % NZCO)*CO_G;
  const int pxg = t % NPXG, cog = t / NPXG;
  const int r0 = pxg / NROWG;
  const int c8 = (pxg % NROWG)*PX;
  const int cot0 = cog*CO_T;
  const int gx0 = bx*TW, gy0 = by*TH;
  float acc[CO_T*PX];
  #pragma unroll
  for (int i=0;i<CO_T*PX;i++) acc[i]=0.f;
  for (int ci0=0; ci0<CIN; ci0+=CI_C){
    __syncthreads();
    for (int e=t; e<CI_C*(TH+2)*TWP; e+=NTHR){
      int ci = e / ((TH+2)*TWP); int rem = e - ci*((TH+2)*TWP);
      int r = rem / TWP; int cx = rem - r*TWP;
      int gy = gy0 + r - 1, gx = gx0 + cx - 1;
      float v = 0.f;
      if (gy>=0 && gy<HH && gx>=0 && gx<WW)
        v = in[(((size_t)n*CIN + ci0+ci)*HH + gy)*WW + gx];
      in_t[ci][r][cx] = v;
    }
    for (int e=t; e<CI_C*9*CO_G; e+=NTHR){
      int ci = e / (9*CO_G); int rem = e - ci*(9*CO_G);
      int kk = rem / CO_G; int co = rem - kk*CO_G;
      wt[ci][kk][co] = wgt[(((size_t)(co0+co))*CIN + ci0+ci)*9 + kk];
    }
    __syncthreads();
    #pragma unroll
    for (int ci=0; ci<CI_C; ci++){
      #pragma unroll
      for (int ky=0; ky<3; ky++){
        float win[PX+4];
        {
          const float4* rp = (const float4*)&in_t[ci][r0+ky][c8];
          float4 a = rp[0], b = rp[1];
          win[0]=a.x; win[1]=a.y; win[2]=a.z; win[3]=a.w;
          win[4]=b.x; win[5]=b.y; win[6]=b.z; win[7]=b.w;
          if constexpr (PX==8){
            float4 c = rp[2];
            win[8]=c.x; win[9]=c.y; win[10]=c.z; win[11]=c.w;
          }
        }
        #pragma unroll
        for (int kx=0; kx<3; kx++){
          float2 wv = *(const float2*)&wt[ci][ky*3+kx][cot0];
          #pragma unroll
          for (int x=0;x<PX;x++){
            acc[0*PX+x] = fmaf(wv.x, win[kx+x], acc[0*PX+x]);
            acc[1*PX+x] = fmaf(wv.y, win[kx+x], acc[1*PX+x]);
          }
        }
      }
    }
  }
  const int yy = gy0 + r0, xx0 = gx0 + c8;
  if constexpr (!OUT_NLC){
    #pragma unroll
    for (int c=0;c<CO_T;c++){
      const float bv = bias[co0+cot0+c];
      float v[PX];
      #pragma unroll
      for (int x=0;x<PX;x++){
        float vv = acc[c*PX+x] + bv;
        v[x] = RELU ? fmaxf(vv, 0.f) : vv;
      }
      float* op = &out[(((size_t)n*CO_TOT + co0+cot0+c)*HH + yy)*WW + xx0];
      #pragma unroll
      for (int x4=0; x4<PX/4; x4++)
        *(float4*)&op[x4*4] = make_float4(v[x4*4],v[x4*4+1],v[x4*4+2],v[x4*4+3]);
    }
  } else {
    #pragma unroll
    for (int x=0;x<PX;x++){
      float2 v;
      float b0 = bias[co0+cot0], b1 = bias[co0+cot0+1];
      v.x = acc[0*PX+x] + b0;
      v.y = acc[1*PX+x] + b1;
      if (RELU){ v.x = fmaxf(v.x,0.f); v.y = fmaxf(v.y,0.f); }
      *(float2*)&out[((size_t)n*LL + yy*WW + xx0+x)*CO_TOT + cot0] = v;
    }
  }
}

// ---------------- 1x1 conv (ye), output [N][L][64] --------------------------
__global__ __launch_bounds__(256) void k_conv1x1(const float* __restrict__ x2,
    const float* __restrict__ wa, const float* __restrict__ ba,
    float* __restrict__ ye){
  __shared__ float xs[64][64];
  __shared__ float wts[64][64];
  const int t = threadIdx.x;
  const int n = blockIdx.y;
  const int l0 = blockIdx.x*64;
  for (int e=t; e<4096; e+=256){
    int ci = e >> 6, l = e & 63;
    xs[ci][l]  = x2[((size_t)n*CIN+ci)*LL + l0 + l];
    wts[ci][l] = wa[(size_t)l*64 + ci];          // wts[ci][co]
  }
  __syncthreads();
  const int l = t & 63, cq = t >> 6;
  float acc[16];
  #pragma unroll
  for (int i=0;i<16;i++) acc[i] = ba[cq*16+i];
  for (int ci=0; ci<64; ci++){
    float xv = xs[ci][l];
    #pragma unroll
    for (int i=0;i<16;i++) acc[i] = fmaf(xv, wts[ci][cq*16+i], acc[i]);
  }
  float* op = &ye[((size_t)n*LL + l0 + l)*64 + cq*16];
  #pragma unroll
  for (int i=0;i<16;i++) op[i] = acc[i];
}

// ---------------- LSH codes: argmax over [rot ; -rot] ------------------------
__global__ __launch_bounds__(128) void k_codes(const float* __restrict__ xe,
    const float* __restrict__ rot, unsigned char* __restrict__ codes){
  __shared__ float rs[NHASH][64][16];
  const int t = threadIdx.x;
  for (int e=t; e<4096; e+=128){
    int f = e >> 8; int rem = e & 255;
    int h = rem >> 6; int i = rem & 63;
    rs[h][i][f] = rot[((size_t)f*NHASH + h)*64 + i];
  }
  __syncthreads();
  const int n = blockIdx.y;
  const int l = blockIdx.x*128 + t;
  float q[16];
  const float* xr = &xe[((size_t)n*LL + l)*16];
  #pragma unroll
  for (int f=0;f<16;f++) q[f] = xr[f];
  #pragma unroll
  for (int h=0;h<NHASH;h++){
    float bp = -3.0e38f, bn = -3.0e38f; int ap=0, an=0;
    for (int i=0;i<64;i++){
      float s = 0.f;
      #pragma unroll
      for (int f=0;f<16;f++) s = fmaf(q[f], rs[h][i][f], s);
      if (s > bp){ bp = s; ap = i; }
      if (-s > bn){ bn = -s; an = i; }
    }
    int code = (bp >= bn) ? ap : (64 + an);   // first-index tie rule of argmax
    codes[((size_t)n*NHASH + h)*LL + l] = (unsigned char)code;
  }
}

// ---------------- stable counting sort: hist / scan / rank+scatter ----------
__global__ __launch_bounds__(256) void k_hist(const unsigned char* __restrict__ codes,
    unsigned int* __restrict__ segHist){
  __shared__ unsigned int h[NBUCK];
  const int t = threadIdx.x;
  if (t < NBUCK) h[t] = 0;
  __syncthreads();
  const int n = blockIdx.z, hh = blockIdx.y, s = blockIdx.x;
  const unsigned char* cp = codes + ((size_t)n*NHASH + hh)*LL + (size_t)s*SEGL;
  for (int e=t; e<SEGL; e+=256) atomicAdd(&h[cp[e]], 1u);
  __syncthreads();
  if (t < NBUCK)
    segHist[(((size_t)(n*NHASH+hh))*NSEG + s)*NBUCK + t] = h[t];
}

__global__ __launch_bounds__(128) void k_scan(unsigned int* __restrict__ segHist){
  __shared__ unsigned int tot[NBUCK];
  __shared__ unsigned int base[NBUCK];
  const int b = threadIdx.x;
  const size_t off = (size_t)blockIdx.x * NSEG * NBUCK;
  unsigned int run = 0;
  for (int s=0;s<NSEG;s++){
    unsigned int v = segHist[off + (size_t)s*NBUCK + b];
    segHist[off + (size_t)s*NBUCK + b] = run;
    run += v;
  }
  tot[b] = run;
  __syncthreads();
  if (b==0){ unsigned int r=0; for (int i=0;i<NBUCK;i++){ base[i]=r; r+=tot[i]; } }
  __syncthreads();
  const unsigned int bb = base[b];
  for (int s=0;s<NSEG;s++) segHist[off + (size_t)s*NBUCK + b] += bb;
}

__global__ __launch_bounds__(256) void k_rank(const unsigned char* __restrict__ codes,
    const unsigned int* __restrict__ segHist, int* __restrict__ sortPos,
    int* __restrict__ srtIdx){
  __shared__ unsigned int cw[SEGL/4];
  __shared__ unsigned int sbase[NBUCK];
  const int t = threadIdx.x;
  const int n = blockIdx.z, hh = blockIdx.y, s = blockIdx.x;
  const size_t cb = ((size_t)n*NHASH + hh)*LL + (size_t)s*SEGL;
  const unsigned int* cp32 = (const unsigned int*)(codes + cb);
  for (int e=t; e<SEGL/4; e+=256) cw[e] = cp32[e];
  if (t < NBUCK)
    sbase[t] = segHist[(((size_t)(n*NHASH+hh))*NSEG + s)*NBUCK + t];
  __syncthreads();
  const size_t ob = ((size_t)n*NHASH + hh)*LL;
  for (int e=t; e<SEGL; e+=256){
    unsigned int c = (cw[e>>2] >> ((e&3)*8)) & 0xffu;
    unsigned int mul = c * 0x01010101u;
    int cnt = 0;
    const int nw = e >> 2;
    for (int wi=0; wi<nw; wi++){
      unsigned int v = cw[wi] ^ mul;
      unsigned int t1 = (v & 0x7f7f7f7fu) + 0x7f7f7f7fu;   // exact zero-byte detect
      unsigned int z = ~(t1 | v) & 0x80808080u;
      cnt += __popc(z);
    }
    unsigned int lastw = cw[nw];
    const int nbp = e & 3;
    for (int bp=0; bp<nbp; bp++)
      if (((lastw >> (bp*8)) & 0xffu) == c) cnt++;
    int pos = (int)sbase[c] + cnt;
    int l = s*SEGL + e;
    sortPos[ob + l] = pos;
    srtIdx[ob + pos] = l;
  }
}

// ---------------- attention: MFMA (bf16x2-split QK, bf16 PV) ----------------
__global__ __launch_bounds__(576) void k_attn(const float* __restrict__ xe,
    const float* __restrict__ ye, const int* __restrict__ srtIdx,
    unsigned short* __restrict__ retS, float* __restrict__ bscore){
  extern __shared__ char smem[];
  unsigned short* Kq = (unsigned short*)(smem + AT_KOFF);  // [432][40] bf16
  char* Vt  = smem + AT_VOFF;                              // [64][456] bf16
  char* Pst = smem + AT_POFF;                              // [9][16][40] bf16
  int* lkI  = (int*)(smem + AT_IOFF);                      // [432]

  const int t = threadIdx.x;
  const int k = blockIdx.x, hh = blockIdx.y, n = blockIdx.z;
  const size_t sb = ((size_t)n*NHASH + hh)*LL;
  const int l = t & 63, w = t >> 6;
  const int lq16 = l & 15, g = l >> 4;

  // ---- phase 0: gather indices + stage normalized split-K ----
  if (t < 432){
    const int c3 = t / CHK, jl = t - c3*CHK;
    const int kc = (c3==0) ? k : ((c3==1) ? ((k+NCHK-1)&(NCHK-1)) : ((k+1)&(NCHK-1)));
    const int lk = srtIdx[sb + (size_t)kc*CHK + jl];
    lkI[t] = lk;
    const float4* xr = (const float4*)&xe[((size_t)n*LL + lk)*16];
    float4 v0 = xr[0], v1 = xr[1], v2 = xr[2], v3 = xr[3];
    float f[16] = {v0.x,v0.y,v0.z,v0.w, v1.x,v1.y,v1.z,v1.w,
                   v2.x,v2.y,v2.z,v2.w, v3.x,v3.y,v3.z,v3.w};
    float ss = 0.f;
    #pragma unroll
    for (int i=0;i<16;i++) ss = fmaf(f[i], f[i], ss);
    const float inv = 1.f / fmaxf(sqrtf(ss), 5e-5f);
    #pragma unroll
    for (int i=0;i<16;i++) f[i] *= inv;
    unsigned int kh[8], klo[8];
    #pragma unroll
    for (int i=0;i<8;i++) kh[i] = cvtpk_bf16(f[2*i], f[2*i+1]);
    #pragma unroll
    for (int i=0;i<8;i++)
      klo[i] = cvtpk_bf16(f[2*i] - bfl(kh[i]), f[2*i+1] - bfh(kh[i]));
    int4* kr = (int4*)((char*)Kq + t*K_ROWB);
    kr[0] = make_int4((int)kh[0],(int)kh[1],(int)kh[2],(int)kh[3]);
    kr[1] = make_int4((int)kh[4],(int)kh[5],(int)kh[6],(int)kh[7]);
    kr[2] = make_int4((int)klo[0],(int)klo[1],(int)klo[2],(int)klo[3]);
    kr[3] = make_int4((int)klo[4],(int)klo[5],(int)klo[6],(int)klo[7]);
  }
  // zero phantom V columns j=432..447
  if (t < 512){
    int c = t >> 3, jp = t & 7;
    *(unsigned int*)(Vt + c*V_ROWB + 864 + jp*4) = 0u;
  }
  __syncthreads();

  // ---- phase 1: stage V^T (bf16, [c][j]) + build Q fragments ----
  #pragma unroll 4
  for (int it=0; it<24; ++it){
    const int e = t + it*576;
    const int jp = e >> 6, c = e & 63;
    const float a = ye[((size_t)n*LL + lkI[2*jp  ])*64 + c];
    const float b = ye[((size_t)n*LL + lkI[2*jp+1])*64 + c];
    *(unsigned int*)(Vt + c*V_ROWB + jp*4) = cvtpk_bf16(a, b);
  }
  const int qg = w*16 + lq16;
  const int pq = k*CHK + qg;
  FragU b1, b2;
  {
    const int lq = lkI[qg];
    const float4* qp = (const float4*)&xe[((size_t)n*LL + lq)*16 + (size_t)(g&1)*8];
    float4 qa = qp[0], qb = qp[1];
    b1.u[0] = cvtpk_bf16(qa.x, qa.y); b1.u[1] = cvtpk_bf16(qa.z, qa.w);
    b1.u[2] = cvtpk_bf16(qb.x, qb.y); b1.u[3] = cvtpk_bf16(qb.z, qb.w);
    if (g < 2){
      b2.u[0] = cvtpk_bf16(qa.x - bfl(b1.u[0]), qa.y - bfh(b1.u[0]));
      b2.u[1] = cvtpk_bf16(qa.z - bfl(b1.u[1]), qa.w - bfh(b1.u[1]));
      b2.u[2] = cvtpk_bf16(qb.x - bfl(b1.u[2]), qb.y - bfh(b1.u[2]));
      b2.u[3] = cvtpk_bf16(qb.z - bfl(b1.u[3]), qb.w - bfh(b1.u[3]));
    } else {
      b2.u[0]=0u; b2.u[1]=0u; b2.u[2]=0u; b2.u[3]=0u;
    }
  }
  __syncthreads();

  // ---- pass 1: exact per-q max over all 432 keys ----
  const char* Kb = (const char*)Kq + lq16*K_ROWB + g*16;
  float m = -3.0e38f;
  for (int t27=0; t27<27; ++t27){
    FragU a; a.i = *(const int4*)(Kb + (size_t)t27*16*K_ROWB);
    f32x4 C = {0.f,0.f,0.f,0.f};
    C = __builtin_amdgcn_mfma_f32_16x16x32_bf16(a.s, b2.s, C, 0, 0, 0);
    C = __builtin_amdgcn_mfma_f32_16x16x32_bf16(a.s, b1.s, C, 0, 0, 0);
    m = fmaxf(m, fmaxf(fmaxf(C[0],C[1]), fmaxf(C[2],C[3])));
  }
  m = fmaxf(m, __shfl_xor(m, 16));
  m = fmaxf(m, __shfl_xor(m, 32));

  // ---- pass 2: recompute S, P=exp(S-m), accumulate sum and O^T = V^T P^T ----
  float sum = 0.f;
  f32x4 O0 = {0.f,0.f,0.f,0.f}, O1 = O0, O2 = O0, O3 = O0;
  char* Pw = Pst + w*1280;
  for (int u=0; u<14; ++u){
    #pragma unroll
    for (int sub=0; sub<2; ++sub){
      const int t27 = u*2 + sub;
      uint2 pw;
      if (t27 < 27){
        FragU a; a.i = *(const int4*)(Kb + (size_t)t27*16*K_ROWB);
        f32x4 C = {0.f,0.f,0.f,0.f};
        C = __builtin_amdgcn_mfma_f32_16x16x32_bf16(a.s, b2.s, C, 0, 0, 0);
        C = __builtin_amdgcn_mfma_f32_16x16x32_bf16(a.s, b1.s, C, 0, 0, 0);
        const float p0 = __expf(C[0]-m), p1 = __expf(C[1]-m);
        const float p2 = __expf(C[2]-m), p3 = __expf(C[3]-m);
        sum += (p0+p1) + (p2+p3);
        pw = make_uint2(cvtpk_bf16(p0,p1), cvtpk_bf16(p2,p3));
      } else {
        pw = make_uint2(0u, 0u);
      }
      *(uint2*)(Pw + lq16*K_ROWB + sub*32 + g*8) = pw;
    }
    asm volatile("s_waitcnt lgkmcnt(0)" ::: "memory");
    __builtin_amdgcn_sched_barrier(0);
    FragU bp; bp.i = *(const int4*)(Pw + lq16*K_ROWB + g*16);
    const char* Vb = Vt + lq16*V_ROWB + u*64 + g*16;
    FragU av;
    av.i = *(const int4*)(Vb);            O0 = __builtin_amdgcn_mfma_f32_16x16x32_bf16(av.s, bp.s, O0, 0,0,0);
    av.i = *(const int4*)(Vb + 16*V_ROWB); O1 = __builtin_amdgcn_mfma_f32_16x16x32_bf16(av.s, bp.s, O1, 0,0,0);
    av.i = *(const int4*)(Vb + 32*V_ROWB); O2 = __builtin_amdgcn_mfma_f32_16x16x32_bf16(av.s, bp.s, O2, 0,0,0);
    av.i = *(const int4*)(Vb + 48*V_ROWB); O3 = __builtin_amdgcn_mfma_f32_16x16x32_bf16(av.s, bp.s, O3, 0,0,0);
  }
  sum += __shfl_xor(sum, 16);
  sum += __shfl_xor(sum, 32);
  const float linv = 1.f / sum;

  unsigned short* op = &retS[(sb + pq)*64];
  {
    uint2 s0 = make_uint2(cvtpk_bf16(O0[0]*linv, O0[1]*linv), cvtpk_bf16(O0[2]*linv, O0[3]*linv));
    uint2 s1 = make_uint2(cvtpk_bf16(O1[0]*linv, O1[1]*linv), cvtpk_bf16(O1[2]*linv, O1[3]*linv));
    uint2 s2 = make_uint2(cvtpk_bf16(O2[0]*linv, O2[1]*linv), cvtpk_bf16(O2[2]*linv, O2[3]*linv));
    uint2 s3 = make_uint2(cvtpk_bf16(O3[0]*linv, O3[1]*linv), cvtpk_bf16(O3[2]*linv, O3[3]*linv));
    *(uint2*)(op +  0 + g*4) = s0;
    *(uint2*)(op + 16 + g*4) = s1;
    *(uint2*)(op + 32 + g*4) = s2;
    *(uint2*)(op + 48 + g*4) = s3;
  }
  if (g == 0) bscore[sb + pq] = m + logf(sum);
}

// ---------------- unsort + hash-softmax combine + residual -------------------
__global__ __launch_bounds__(256) void k_combine(const unsigned short* __restrict__ retS,
    const float* __restrict__ bscore, const int* __restrict__ sortPos,
    const float* __restrict__ x2, float* __restrict__ out){
  const int idx = blockIdx.x*256 + threadIdx.x;
  if (idx >= NB*LL) return;
  const int l = idx % LL, n = idx / LL;
  float bs[NHASH]; int pp[NHASH];
  #pragma unroll
  for (int h=0;h<NHASH;h++){
    size_t sb = ((size_t)n*NHASH + h)*LL;
    int p = sortPos[sb + l];
    pp[h] = p; bs[h] = bscore[sb + p];
  }
  float m = fmaxf(fmaxf(bs[0],bs[1]), fmaxf(bs[2],bs[3]));
  float wsum = 0.f; float wv[NHASH];
  #pragma unroll
  for (int h=0;h<NHASH;h++){ wv[h] = expf(bs[h]-m); wsum += wv[h]; }
  const float winv = 1.f / wsum;
  float o[64];
  #pragma unroll
  for (int i=0;i<64;i++) o[i]=0.f;
  #pragma unroll
  for (int h=0;h<NHASH;h++){
    const float wh = wv[h]*winv;
    const uint4* rp = (const uint4*)&retS[(((size_t)n*NHASH + h)*LL + pp[h])*64];
    #pragma unroll
    for (int i2=0;i2<8;i2++){
      uint4 v = rp[i2];
      o[i2*8+0] = fmaf(wh, bfl(v.x), o[i2*8+0]);
      o[i2*8+1] = fmaf(wh, bfh(v.x), o[i2*8+1]);
      o[i2*8+2] = fmaf(wh, bfl(v.y), o[i2*8+2]);
      o[i2*8+3] = fmaf(wh, bfh(v.y), o[i2*8+3]);
      o[i2*8+4] = fmaf(wh, bfl(v.z), o[i2*8+4]);
      o[i2*8+5] = fmaf(wh, bfh(v.z), o[i2*8+5]);
      o[i2*8+6] = fmaf(wh, bfl(v.w), o[i2*8+6]);
      o[i2*8+7] = fmaf(wh, bfh(v.w), o[i2*8+7]);
    }
  }
  #pragma unroll
  for (int c=0;c<64;c++){
    size_t oi = ((size_t)n*64 + c)*LL + l;
    out[oi] = o[c] + x2[oi];
  }
}

extern "C" void kernel_launch(void* const* d_in, const int* in_sizes, int n_in,
                              void* d_out, int out_size, void* d_ws, size_t ws_size,
                              hipStream_t stream){
  const float* x   = (const float*)d_in[0];
  const float* w1  = (const float*)d_in[1];
  const float* b1  = (const float*)d_in[2];
  const float* w2  = (const float*)d_in[3];
  const float* b2  = (const float*)d_in[4];
  const float* wm  = (const float*)d_in[5];
  const float* bm  = (const float*)d_in[6];
  const float* wa  = (const float*)d_in[7];
  const float* ba  = (const float*)d_in[8];
  const float* rot = (const float*)d_in[9];
  float* outp = (float*)d_out;
  char* ws = (char*)d_ws;
  const size_t FM = (size_t)NB*CIN*HH*WW*sizeof(float);   // 18,874,368 B
  float* x0u = (float*)(ws + 0);
  float* y1  = (float*)(ws + FM);
  float* x2  = (float*)(ws + 2*FM);
  float* xe  = (float*)(ws + 3*FM);
  float* ye  = (float*)(ws + 3*FM + (size_t)NB*LL*CE*sizeof(float));
  char* p = ws + 3*FM + (size_t)NB*LL*CE*sizeof(float) + FM;
  unsigned char* codes = (unsigned char*)p; p += (size_t)NB*NHASH*LL;
  unsigned int* segHist = (unsigned int*)p; p += (size_t)NB*NHASH*NSEG*NBUCK*sizeof(unsigned int);
  int* sortPos = (int*)p; p += (size_t)NB*NHASH*LL*sizeof(int);
  int* srtIdx  = (int*)p; p += (size_t)NB*NHASH*LL*sizeof(int);
  float* bscore = (float*)p; p += (size_t)NB*NHASH*LL*sizeof(float);
  unsigned short* retS = (unsigned short*)ws;  // reuse x0u+y1 (exactly 2*FM)
  if (ws_size < (size_t)(p - ws)) return;      // ~84.3 MB required

  hipFuncSetAttribute((const void*)k_attn,
                      hipFuncAttributeMaxDynamicSharedMemorySize, AT_LDS);

  k_upsample<<<dim3((NB*CIN*HH*WW+255)/256), dim3(256), 0, stream>>>(x, x0u);
  k_conv3v2<64,16,8,32,16,true,false><<<dim3(WW/32, HH/16, NB*4), dim3(512), 0, stream>>>(x0u, w1, b1, y1);
  k_conv3v2<64,16,8,32,16,true,false><<<dim3(WW/32, HH/16, NB*4), dim3(512), 0, stream>>>(y1, w2, b2, x2);
  k_conv3v2<16,16,4,16,16,false,true><<<dim3(WW/16, HH/16, NB), dim3(512), 0, stream>>>(x2, wm, bm, xe);
  k_conv1x1<<<dim3(LL/64, NB), dim3(256), 0, stream>>>(x2, wa, ba, ye);
  k_codes<<<dim3(LL/128, NB), dim3(128), 0, stream>>>(xe, rot, codes);
  k_hist<<<dim3(NSEG, NHASH, NB), dim3(256), 0, stream>>>(codes, segHist);
  k_scan<<<dim3(NB*NHASH), dim3(128), 0, stream>>>(segHist);
  k_rank<<<dim3(NSEG, NHASH, NB), dim3(256), 0, stream>>>(codes, segHist, sortPos, srtIdx);
  k_attn<<<dim3(NCHK, NHASH, NB), dim3(576), AT_LDS, stream>>>(xe, ye, srtIdx, retS, bscore);
  k_combine<<<dim3((NB*LL+255)/256), dim3(256), 0, stream>>>(retS, bscore, sortPos, x2, outp);
}

// Round 4
// 411.804 us; speedup vs baseline: 3.9208x; 1.5628x over previous
//
#include <hip/hip_runtime.h>
#include <math.h>

#define NB 2
#define CIN 64
#define H0 96
#define W0 96
#define HH 192
#define WW 192
#define LL (HH*WW)        // 36864
#define NHASH 4
#define CHK 144
#define NCHK 256          // LL/CHK
#define CE 16
#define CV 64
#define NBUCK 128
#define SEGL 576
#define NSEG 64           // LL/SEGL

// ---- attention LDS layout (bytes) ----
#define K_ROWB   80
#define V_ROWB   912
#define AT_KOFF  0
#define AT_VOFF  34560
#define AT_POFF  92928
#define AT_IOFF  104448
#define AT_LDS   106176

typedef __attribute__((ext_vector_type(8))) short short8_t;
typedef __attribute__((ext_vector_type(4))) float f32x4;
union FragU { unsigned int u[4]; int4 i; short8_t s; };

__device__ __forceinline__ unsigned int cvtpk_bf16(float a, float b){
  unsigned int r;
  asm("v_cvt_pk_bf16_f32 %0, %1, %2" : "=v"(r) : "v"(a), "v"(b));
  return r;
}
__device__ __forceinline__ float bfl(unsigned int u){ return __uint_as_float(u << 16); }
__device__ __forceinline__ float bfh(unsigned int u){ return __uint_as_float(u & 0xffff0000u); }

// ---------------- bicubic 2x upsample (separable, edge pad) ----------------
__global__ __launch_bounds__(256) void k_upsample(const float* __restrict__ x,
                                                  float* __restrict__ out){
  int idx = blockIdx.x*256 + threadIdx.x;
  if (idx >= NB*CIN*HH*WW) return;
  int ox = idx % WW; int t2 = idx / WW;
  int oy = t2 % HH;  t2 /= HH;
  int i = oy >> 1, a = oy & 1;
  int j = ox >> 1, b = ox & 1;
  const float e0=-0.03515625f, e1=0.26171875f, e2=0.87890625f, e3=-0.10546875f;
  float wy[4], wx[4]; int ty[4], tx[4];
  if (a){ wy[0]=e3; wy[1]=e2; wy[2]=e1; wy[3]=e0; } else { wy[0]=e0; wy[1]=e1; wy[2]=e2; wy[3]=e3; }
  if (b){ wx[0]=e3; wx[1]=e2; wx[2]=e1; wx[3]=e0; } else { wx[0]=e0; wx[1]=e1; wx[2]=e2; wx[3]=e3; }
  int offy = a ? -1 : -2, offx = b ? -1 : -2;
  #pragma unroll
  for (int k=0;k<4;k++){
    int t = i + offy + k; ty[k] = t<0?0:(t>H0-1?H0-1:t);
    int s = j + offx + k; tx[k] = s<0?0:(s>W0-1?W0-1:s);
  }
  const float* xp = x + (size_t)t2*H0*W0;
  float s = 0.f;
  #pragma unroll
  for (int ky=0;ky<4;ky++){
    const float* row = xp + ty[ky]*W0;
    float rs = 0.f;
    rs = fmaf(wx[0], row[tx[0]], rs);
    rs = fmaf(wx[1], row[tx[1]], rs);
    rs = fmaf(wx[2], row[tx[2]], rs);
    rs = fmaf(wx[3], row[tx[3]], rs);
    s = fmaf(wy[ky], rs, s);
  }
  out[idx] = s;
}

// ---------------- weight prep: fp32 OIHW -> bf16x2 frag layout ---------------
// wsT[tap][half][term][co][kg][e], e over 8 ci, ci = half*32+kg*8+e
__global__ __launch_bounds__(256) void k_prepw(const float* __restrict__ w,
    unsigned short* __restrict__ wsT, int CO){
  int idx = blockIdx.x*256 + threadIdx.x;
  if (idx >= CO*64*9) return;
  int tap = idx % 9; int rem = idx / 9;
  int ci = rem % 64; int co = rem / 64;
  float v = w[(size_t)(co*64 + ci)*9 + tap];
  unsigned int hu = cvtpk_bf16(v, v) & 0xffffu;
  float hf = bfl(hu);
  unsigned int lu = cvtpk_bf16(v - hf, 0.f) & 0xffffu;
  int half = ci >> 5, kg = (ci >> 3) & 3, e = ci & 7;
  size_t base = ((size_t)(tap*2 + half)*2)*CO*32 + ((size_t)co*4 + kg)*8 + e;
  wsT[base]         = (unsigned short)hu;
  wsT[base + (size_t)CO*32] = (unsigned short)lu;
}

// ---------------- 3x3 conv via MFMA, bf16x3 emulated fp32 --------------------
// block 256 thr = 4 waves; out tile = 1 row x 64 px x CO; wave w: px-tile w*16.
// LDS: input h/l [3 rows][66 cols][64 ci], ci-group XOR (col&7) swizzle.
template<int CO, bool RELU, bool OUT_NLC>
__global__ __launch_bounds__(256) void k_conv3m(const float* __restrict__ in,
    const unsigned short* __restrict__ wsT, const float* __restrict__ bias,
    float* __restrict__ out){
  __shared__ unsigned short inH[3][66][64];
  __shared__ unsigned short inL[3][66][64];
  const int t = threadIdx.x;
  const int bx = blockIdx.x, y = blockIdx.y, n = blockIdx.z;
  const int x0 = bx*64;
  const int l = t & 63, w = t >> 6;
  const int lq = l & 15, kg = l >> 4;

  // ---- staging: 192 strips (row,ci) x 16 float4-chunks ----
  for (int e = t; e < 3072; e += 256){
    const int chunk = e & 15;
    const int strip = e >> 4;
    const int ci = strip & 63, row = strip >> 6;
    const int gy = y + row - 1;
    float4 v = make_float4(0.f,0.f,0.f,0.f);
    if (gy >= 0 && gy < HH)
      v = *(const float4*)&in[(((size_t)n*CIN + ci)*HH + gy)*WW + x0 + chunk*4];
    float vv[4] = {v.x, v.y, v.z, v.w};
    #pragma unroll
    for (int j = 0; j < 4; ++j){
      const int col = 1 + chunk*4 + j;
      const int sci = (((ci >> 3) ^ (col & 7)) << 3) | (ci & 7);
      unsigned int hu = cvtpk_bf16(vv[j], vv[j]);
      unsigned int lu = cvtpk_bf16(vv[j] - bfl(hu), 0.f);
      inH[row][col][sci] = (unsigned short)hu;
      inL[row][col][sci] = (unsigned short)lu;
    }
  }
  if (t < 192){
    const int ci = t & 63, row = t >> 6;
    const int gy = y + row - 1;
    const bool okY = (gy >= 0 && gy < HH);
    const float* ip = &in[(((size_t)n*CIN + ci)*HH + (size_t)(okY?gy:0))*WW];
    float vL = (okY && x0 >= 1) ? ip[x0-1] : 0.f;
    float vR = (okY && x0+64 < WW) ? ip[x0+64] : 0.f;
    unsigned int hL = cvtpk_bf16(vL, vL);
    unsigned int lLu = cvtpk_bf16(vL - bfl(hL), 0.f);
    unsigned int hR = cvtpk_bf16(vR, vR);
    unsigned int lRu = cvtpk_bf16(vR - bfl(hR), 0.f);
    const int sci0 = ci;                                  // col0: ^0
    const int sci65 = (((ci >> 3) ^ 1) << 3) | (ci & 7);  // col65: 65&7=1
    inH[row][0][sci0]  = (unsigned short)hL;  inL[row][0][sci0]  = (unsigned short)lLu;
    inH[row][65][sci65] = (unsigned short)hR; inL[row][65][sci65] = (unsigned short)lRu;
  }
  __syncthreads();

  constexpr int NCT = CO/16;
  f32x4 acc[NCT];
  #pragma unroll
  for (int c=0;c<NCT;c++) acc[c] = (f32x4){0.f,0.f,0.f,0.f};
  const unsigned short* wlane = wsT + (size_t)lq*32 + (size_t)kg*8;

  #pragma unroll
  for (int tap=0; tap<9; ++tap){
    const int ky = tap/3, kx = tap - ky*3;
    const int col = w*16 + lq + kx;
    #pragma unroll
    for (int half=0; half<2; ++half){
      const int sci = ((((half<<2) | kg) ^ (col & 7)) << 3);
      FragU Bh, Bl;
      Bh.i = *(const int4*)&inH[ky][col][sci];
      Bl.i = *(const int4*)&inL[ky][col][sci];
      const unsigned short* wth = wlane + (size_t)((tap*2+half)*2)*CO*32;
      #pragma unroll
      for (int ct=0; ct<NCT; ++ct){
        FragU Ah, Al;
        Ah.i = *(const int4*)(wth + ct*512);
        Al.i = *(const int4*)(wth + CO*32 + ct*512);
        acc[ct] = __builtin_amdgcn_mfma_f32_16x16x32_bf16(Ah.s, Bl.s, acc[ct], 0,0,0);
        acc[ct] = __builtin_amdgcn_mfma_f32_16x16x32_bf16(Al.s, Bh.s, acc[ct], 0,0,0);
        acc[ct] = __builtin_amdgcn_mfma_f32_16x16x32_bf16(Ah.s, Bh.s, acc[ct], 0,0,0);
      }
    }
  }

  const int px = x0 + w*16 + lq;
  if constexpr (!OUT_NLC){
    #pragma unroll
    for (int ct=0; ct<NCT; ++ct){
      #pragma unroll
      for (int r=0; r<4; ++r){
        const int co = ct*16 + kg*4 + r;
        float v = acc[ct][r] + bias[co];
        if (RELU) v = fmaxf(v, 0.f);
        out[(((size_t)n*CO + co)*HH + y)*WW + px] = v;
      }
    }
  } else {
    #pragma unroll
    for (int r=0; r<4; ++r){
      const int co = kg*4 + r;
      float v = acc[0][r] + bias[co];
      if (RELU) v = fmaxf(v, 0.f);
      out[((size_t)n*LL + y*WW + px)*CO + co] = v;
    }
  }
}

// ---------------- 1x1 conv (ye), output [N][L][64] --------------------------
__global__ __launch_bounds__(256) void k_conv1x1(const float* __restrict__ x2,
    const float* __restrict__ wa, const float* __restrict__ ba,
    float* __restrict__ ye){
  __shared__ float xs[64][64];
  __shared__ float wts[64][64];
  const int t = threadIdx.x;
  const int n = blockIdx.y;
  const int l0 = blockIdx.x*64;
  for (int e=t; e<4096; e+=256){
    int ci = e >> 6, l = e & 63;
    xs[ci][l]  = x2[((size_t)n*CIN+ci)*LL + l0 + l];
    wts[ci][l] = wa[(size_t)l*64 + ci];
  }
  __syncthreads();
  const int l = t & 63, cq = t >> 6;
  float acc[16];
  #pragma unroll
  for (int i=0;i<16;i++) acc[i] = ba[cq*16+i];
  for (int ci=0; ci<64; ci++){
    float xv = xs[ci][l];
    #pragma unroll
    for (int i=0;i<16;i++) acc[i] = fmaf(xv, wts[ci][cq*16+i], acc[i]);
  }
  float* op = &ye[((size_t)n*LL + l0 + l)*64 + cq*16];
  #pragma unroll
  for (int i=0;i<16;i++) op[i] = acc[i];
}

// ---------------- LSH codes: argmax over [rot ; -rot] ------------------------
__global__ __launch_bounds__(128) void k_codes(const float* __restrict__ xe,
    const float* __restrict__ rot, unsigned char* __restrict__ codes){
  __shared__ float rs[NHASH][64][16];
  const int t = threadIdx.x;
  for (int e=t; e<4096; e+=128){
    int f = e >> 8; int rem = e & 255;
    int h = rem >> 6; int i = rem & 63;
    rs[h][i][f] = rot[((size_t)f*NHASH + h)*64 + i];
  }
  __syncthreads();
  const int n = blockIdx.y;
  const int l = blockIdx.x*128 + t;
  float q[16];
  const float* xr = &xe[((size_t)n*LL + l)*16];
  #pragma unroll
  for (int f=0;f<16;f++) q[f] = xr[f];
  #pragma unroll
  for (int h=0;h<NHASH;h++){
    float bp = -3.0e38f, bn = -3.0e38f; int ap=0, an=0;
    for (int i=0;i<64;i++){
      float s = 0.f;
      #pragma unroll
      for (int f=0;f<16;f++) s = fmaf(q[f], rs[h][i][f], s);
      if (s > bp){ bp = s; ap = i; }
      if (-s > bn){ bn = -s; an = i; }
    }
    int code = (bp >= bn) ? ap : (64 + an);
    codes[((size_t)n*NHASH + h)*LL + l] = (unsigned char)code;
  }
}

// ---------------- stable counting sort: hist / scan / rank+scatter ----------
__global__ __launch_bounds__(256) void k_hist(const unsigned char* __restrict__ codes,
    unsigned int* __restrict__ segHist){
  __shared__ unsigned int h[NBUCK];
  const int t = threadIdx.x;
  if (t < NBUCK) h[t] = 0;
  __syncthreads();
  const int n = blockIdx.z, hh = blockIdx.y, s = blockIdx.x;
  const unsigned char* cp = codes + ((size_t)n*NHASH + hh)*LL + (size_t)s*SEGL;
  for (int e=t; e<SEGL; e+=256) atomicAdd(&h[cp[e]], 1u);
  __syncthreads();
  if (t < NBUCK)
    segHist[(((size_t)(n*NHASH+hh))*NSEG + s)*NBUCK + t] = h[t];
}

__global__ __launch_bounds__(128) void k_scan(unsigned int* __restrict__ segHist){
  __shared__ unsigned int tot[NBUCK];
  __shared__ unsigned int base[NBUCK];
  const int b = threadIdx.x;
  const size_t off = (size_t)blockIdx.x * NSEG * NBUCK;
  unsigned int run = 0;
  for (int s=0;s<NSEG;s++){
    unsigned int v = segHist[off + (size_t)s*NBUCK + b];
    segHist[off + (size_t)s*NBUCK + b] = run;
    run += v;
  }
  tot[b] = run;
  __syncthreads();
  if (b==0){ unsigned int r=0; for (int i=0;i<NBUCK;i++){ base[i]=r; r+=tot[i]; } }
  __syncthreads();
  const unsigned int bb = base[b];
  for (int s=0;s<NSEG;s++) segHist[off + (size_t)s*NBUCK + b] += bb;
}

__global__ __launch_bounds__(256) void k_rank(const unsigned char* __restrict__ codes,
    const unsigned int* __restrict__ segHist, int* __restrict__ sortPos,
    int* __restrict__ srtIdx){
  __shared__ unsigned int cw[SEGL/4];
  __shared__ unsigned int sbase[NBUCK];
  const int t = threadIdx.x;
  const int n = blockIdx.z, hh = blockIdx.y, s = blockIdx.x;
  const size_t cb = ((size_t)n*NHASH + hh)*LL + (size_t)s*SEGL;
  const unsigned int* cp32 = (const unsigned int*)(codes + cb);
  for (int e=t; e<SEGL/4; e+=256) cw[e] = cp32[e];
  if (t < NBUCK)
    sbase[t] = segHist[(((size_t)(n*NHASH+hh))*NSEG + s)*NBUCK + t];
  __syncthreads();
  const size_t ob = ((size_t)n*NHASH + hh)*LL;
  for (int e=t; e<SEGL; e+=256){
    unsigned int c = (cw[e>>2] >> ((e&3)*8)) & 0xffu;
    unsigned int mul = c * 0x01010101u;
    int cnt = 0;
    const int nw = e >> 2;
    for (int wi=0; wi<nw; wi++){
      unsigned int v = cw[wi] ^ mul;
      unsigned int t1 = (v & 0x7f7f7f7fu) + 0x7f7f7f7fu;
      unsigned int z = ~(t1 | v) & 0x80808080u;
      cnt += __popc(z);
    }
    unsigned int lastw = cw[nw];
    const int nbp = e & 3;
    for (int bp=0; bp<nbp; bp++)
      if (((lastw >> (bp*8)) & 0xffu) == c) cnt++;
    int pos = (int)sbase[c] + cnt;
    int l = s*SEGL + e;
    sortPos[ob + l] = pos;
    srtIdx[ob + pos] = l;
  }
}

// ---------------- attention: MFMA (bf16x2-split QK, bf16 PV) ----------------
__global__ __launch_bounds__(576) void k_attn(const float* __restrict__ xe,
    const float* __restrict__ ye, const int* __restrict__ srtIdx,
    unsigned short* __restrict__ retS, float* __restrict__ bscore){
  extern __shared__ char smem[];
  unsigned short* Kq = (unsigned short*)(smem + AT_KOFF);
  char* Vt  = smem + AT_VOFF;
  char* Pst = smem + AT_POFF;
  int* lkI  = (int*)(smem + AT_IOFF);

  const int t = threadIdx.x;
  const int k = blockIdx.x, hh = blockIdx.y, n = blockIdx.z;
  const size_t sb = ((size_t)n*NHASH + hh)*LL;
  const int l = t & 63, w = t >> 6;
  const int lq16 = l & 15, g = l >> 4;

  if (t < 432){
    const int c3 = t / CHK, jl = t - c3*CHK;
    const int kc = (c3==0) ? k : ((c3==1) ? ((k+NCHK-1)&(NCHK-1)) : ((k+1)&(NCHK-1)));
    const int lk = srtIdx[sb + (size_t)kc*CHK + jl];
    lkI[t] = lk;
    const float4* xr = (const float4*)&xe[((size_t)n*LL + lk)*16];
    float4 v0 = xr[0], v1 = xr[1], v2 = xr[2], v3 = xr[3];
    float f[16] = {v0.x,v0.y,v0.z,v0.w, v1.x,v1.y,v1.z,v1.w,
                   v2.x,v2.y,v2.z,v2.w, v3.x,v3.y,v3.z,v3.w};
    float ss = 0.f;
    #pragma unroll
    for (int i=0;i<16;i++) ss = fmaf(f[i], f[i], ss);
    const float inv = 1.f / fmaxf(sqrtf(ss), 5e-5f);
    #pragma unroll
    for (int i=0;i<16;i++) f[i] *= inv;
    unsigned int kh[8], klo[8];
    #pragma unroll
    for (int i=0;i<8;i++) kh[i] = cvtpk_bf16(f[2*i], f[2*i+1]);
    #pragma unroll
    for (int i=0;i<8;i++)
      klo[i] = cvtpk_bf16(f[2*i] - bfl(kh[i]), f[2*i+1] - bfh(kh[i]));
    int4* kr = (int4*)((char*)Kq + t*K_ROWB);
    kr[0] = make_int4((int)kh[0],(int)kh[1],(int)kh[2],(int)kh[3]);
    kr[1] = make_int4((int)kh[4],(int)kh[5],(int)kh[6],(int)kh[7]);
    kr[2] = make_int4((int)klo[0],(int)klo[1],(int)klo[2],(int)klo[3]);
    kr[3] = make_int4((int)klo[4],(int)klo[5],(int)klo[6],(int)klo[7]);
  }
  if (t < 512){
    int c = t >> 3, jp = t & 7;
    *(unsigned int*)(Vt + c*V_ROWB + 864 + jp*4) = 0u;
  }
  __syncthreads();

  #pragma unroll 4
  for (int it=0; it<24; ++it){
    const int e = t + it*576;
    const int jp = e >> 6, c = e & 63;
    const float a = ye[((size_t)n*LL + lkI[2*jp  ])*64 + c];
    const float b = ye[((size_t)n*LL + lkI[2*jp+1])*64 + c];
    *(unsigned int*)(Vt + c*V_ROWB + jp*4) = cvtpk_bf16(a, b);
  }
  const int qg = w*16 + lq16;
  const int pq = k*CHK + qg;
  FragU b1, b2;
  {
    const int lq = lkI[qg];
    const float4* qp = (const float4*)&xe[((size_t)n*LL + lq)*16 + (size_t)(g&1)*8];
    float4 qa = qp[0], qb = qp[1];
    b1.u[0] = cvtpk_bf16(qa.x, qa.y); b1.u[1] = cvtpk_bf16(qa.z, qa.w);
    b1.u[2] = cvtpk_bf16(qb.x, qb.y); b1.u[3] = cvtpk_bf16(qb.z, qb.w);
    if (g < 2){
      b2.u[0] = cvtpk_bf16(qa.x - bfl(b1.u[0]), qa.y - bfh(b1.u[0]));
      b2.u[1] = cvtpk_bf16(qa.z - bfl(b1.u[1]), qa.w - bfh(b1.u[1]));
      b2.u[2] = cvtpk_bf16(qb.x - bfl(b1.u[2]), qb.y - bfh(b1.u[2]));
      b2.u[3] = cvtpk_bf16(qb.z - bfl(b1.u[3]), qb.w - bfh(b1.u[3]));
    } else {
      b2.u[0]=0u; b2.u[1]=0u; b2.u[2]=0u; b2.u[3]=0u;
    }
  }
  __syncthreads();

  const char* Kb = (const char*)Kq + lq16*K_ROWB + g*16;
  float m = -3.0e38f;
  for (int t27=0; t27<27; ++t27){
    FragU a; a.i = *(const int4*)(Kb + (size_t)t27*16*K_ROWB);
    f32x4 C = {0.f,0.f,0.f,0.f};
    C = __builtin_amdgcn_mfma_f32_16x16x32_bf16(a.s, b2.s, C, 0, 0, 0);
    C = __builtin_amdgcn_mfma_f32_16x16x32_bf16(a.s, b1.s, C, 0, 0, 0);
    m = fmaxf(m, fmaxf(fmaxf(C[0],C[1]), fmaxf(C[2],C[3])));
  }
  m = fmaxf(m, __shfl_xor(m, 16));
  m = fmaxf(m, __shfl_xor(m, 32));

  float sum = 0.f;
  f32x4 O0 = {0.f,0.f,0.f,0.f}, O1 = O0, O2 = O0, O3 = O0;
  char* Pw = Pst + w*1280;
  for (int u=0; u<14; ++u){
    #pragma unroll
    for (int sub=0; sub<2; ++sub){
      const int t27 = u*2 + sub;
      uint2 pw;
      if (t27 < 27){
        FragU a; a.i = *(const int4*)(Kb + (size_t)t27*16*K_ROWB);
        f32x4 C = {0.f,0.f,0.f,0.f};
        C = __builtin_amdgcn_mfma_f32_16x16x32_bf16(a.s, b2.s, C, 0, 0, 0);
        C = __builtin_amdgcn_mfma_f32_16x16x32_bf16(a.s, b1.s, C, 0, 0, 0);
        const float p0 = __expf(C[0]-m), p1 = __expf(C[1]-m);
        const float p2 = __expf(C[2]-m), p3 = __expf(C[3]-m);
        sum += (p0+p1) + (p2+p3);
        pw = make_uint2(cvtpk_bf16(p0,p1), cvtpk_bf16(p2,p3));
      } else {
        pw = make_uint2(0u, 0u);
      }
      *(uint2*)(Pw + lq16*K_ROWB + sub*32 + g*8) = pw;
    }
    asm volatile("s_waitcnt lgkmcnt(0)" ::: "memory");
    __builtin_amdgcn_sched_barrier(0);
    FragU bp; bp.i = *(const int4*)(Pw + lq16*K_ROWB + g*16);
    const char* Vb = Vt + lq16*V_ROWB + u*64 + g*16;
    FragU av;
    av.i = *(const int4*)(Vb);             O0 = __builtin_amdgcn_mfma_f32_16x16x32_bf16(av.s, bp.s, O0, 0,0,0);
    av.i = *(const int4*)(Vb + 16*V_ROWB); O1 = __builtin_amdgcn_mfma_f32_16x16x32_bf16(av.s, bp.s, O1, 0,0,0);
    av.i = *(const int4*)(Vb + 32*V_ROWB); O2 = __builtin_amdgcn_mfma_f32_16x16x32_bf16(av.s, bp.s, O2, 0,0,0);
    av.i = *(const int4*)(Vb + 48*V_ROWB); O3 = __builtin_amdgcn_mfma_f32_16x16x32_bf16(av.s, bp.s, O3, 0,0,0);
  }
  sum += __shfl_xor(sum, 16);
  sum += __shfl_xor(sum, 32);
  const float linv = 1.f / sum;

  unsigned short* op = &retS[(sb + pq)*64];
  {
    uint2 s0 = make_uint2(cvtpk_bf16(O0[0]*linv, O0[1]*linv), cvtpk_bf16(O0[2]*linv, O0[3]*linv));
    uint2 s1 = make_uint2(cvtpk_bf16(O1[0]*linv, O1[1]*linv), cvtpk_bf16(O1[2]*linv, O1[3]*linv));
    uint2 s2 = make_uint2(cvtpk_bf16(O2[0]*linv, O2[1]*linv), cvtpk_bf16(O2[2]*linv, O2[3]*linv));
    uint2 s3 = make_uint2(cvtpk_bf16(O3[0]*linv, O3[1]*linv), cvtpk_bf16(O3[2]*linv, O3[3]*linv));
    *(uint2*)(op +  0 + g*4) = s0;
    *(uint2*)(op + 16 + g*4) = s1;
    *(uint2*)(op + 32 + g*4) = s2;
    *(uint2*)(op + 48 + g*4) = s3;
  }
  if (g == 0) bscore[sb + pq] = m + logf(sum);
}

// ---------------- unsort + hash-softmax combine + residual -------------------
__global__ __launch_bounds__(256) void k_combine(const unsigned short* __restrict__ retS,
    const float* __restrict__ bscore, const int* __restrict__ sortPos,
    const float* __restrict__ x2, float* __restrict__ out){
  const int idx = blockIdx.x*256 + threadIdx.x;
  if (idx >= NB*LL) return;
  const int l = idx % LL, n = idx / LL;
  float bs[NHASH]; int pp[NHASH];
  #pragma unroll
  for (int h=0;h<NHASH;h++){
    size_t sb = ((size_t)n*NHASH + h)*LL;
    int p = sortPos[sb + l];
    pp[h] = p; bs[h] = bscore[sb + p];
  }
  float m = fmaxf(fmaxf(bs[0],bs[1]), fmaxf(bs[2],bs[3]));
  float wsum = 0.f; float wv[NHASH];
  #pragma unroll
  for (int h=0;h<NHASH;h++){ wv[h] = expf(bs[h]-m); wsum += wv[h]; }
  const float winv = 1.f / wsum;
  float o[64];
  #pragma unroll
  for (int i=0;i<64;i++) o[i]=0.f;
  #pragma unroll
  for (int h=0;h<NHASH;h++){
    const float wh = wv[h]*winv;
    const uint4* rp = (const uint4*)&retS[(((size_t)n*NHASH + h)*LL + pp[h])*64];
    #pragma unroll
    for (int i2=0;i2<8;i2++){
      uint4 v = rp[i2];
      o[i2*8+0] = fmaf(wh, bfl(v.x), o[i2*8+0]);
      o[i2*8+1] = fmaf(wh, bfh(v.x), o[i2*8+1]);
      o[i2*8+2] = fmaf(wh, bfl(v.y), o[i2*8+2]);
      o[i2*8+3] = fmaf(wh, bfh(v.y), o[i2*8+3]);
      o[i2*8+4] = fmaf(wh, bfl(v.z), o[i2*8+4]);
      o[i2*8+5] = fmaf(wh, bfh(v.z), o[i2*8+5]);
      o[i2*8+6] = fmaf(wh, bfl(v.w), o[i2*8+6]);
      o[i2*8+7] = fmaf(wh, bfh(v.w), o[i2*8+7]);
    }
  }
  #pragma unroll
  for (int c=0;c<64;c++){
    size_t oi = ((size_t)n*64 + c)*LL + l;
    out[oi] = o[c] + x2[oi];
  }
}

extern "C" void kernel_launch(void* const* d_in, const int* in_sizes, int n_in,
                              void* d_out, int out_size, void* d_ws, size_t ws_size,
                              hipStream_t stream){
  const float* x   = (const float*)d_in[0];
  const float* w1  = (const float*)d_in[1];
  const float* b1  = (const float*)d_in[2];
  const float* w2  = (const float*)d_in[3];
  const float* b2  = (const float*)d_in[4];
  const float* wm  = (const float*)d_in[5];
  const float* bm  = (const float*)d_in[6];
  const float* wa  = (const float*)d_in[7];
  const float* ba  = (const float*)d_in[8];
  const float* rot = (const float*)d_in[9];
  float* outp = (float*)d_out;
  char* ws = (char*)d_ws;
  const size_t FM = (size_t)NB*CIN*HH*WW*sizeof(float);   // 18,874,368 B
  float* x0u = (float*)(ws + 0);
  float* y1  = (float*)(ws + FM);
  float* x2  = (float*)(ws + 2*FM);
  float* xe  = (float*)(ws + 3*FM);
  float* ye  = (float*)(ws + 3*FM + (size_t)NB*LL*CE*sizeof(float));
  char* p = ws + 3*FM + (size_t)NB*LL*CE*sizeof(float) + FM;
  unsigned char* codes = (unsigned char*)p; p += (size_t)NB*NHASH*LL;
  unsigned int* segHist = (unsigned int*)p; p += (size_t)NB*NHASH*NSEG*NBUCK*sizeof(unsigned int);
  int* sortPos = (int*)p; p += (size_t)NB*NHASH*LL*sizeof(int);
  int* srtIdx  = (int*)p; p += (size_t)NB*NHASH*LL*sizeof(int);
  float* bscore = (float*)p; p += (size_t)NB*NHASH*LL*sizeof(float);
  unsigned short* wsT1 = (unsigned short*)p; p += (size_t)9*2*2*64*32*sizeof(unsigned short);
  unsigned short* wsT2 = (unsigned short*)p; p += (size_t)9*2*2*64*32*sizeof(unsigned short);
  unsigned short* wsTm = (unsigned short*)p; p += (size_t)9*2*2*16*32*sizeof(unsigned short);
  unsigned short* retS = (unsigned short*)ws;  // reuse x0u+y1 (exactly 2*FM)
  if (ws_size < (size_t)(p - ws)) return;      // ~84.6 MB required

  hipFuncSetAttribute((const void*)k_attn,
                      hipFuncAttributeMaxDynamicSharedMemorySize, AT_LDS);

  k_prepw<<<dim3((64*64*9+255)/256), dim3(256), 0, stream>>>(w1, wsT1, 64);
  k_prepw<<<dim3((64*64*9+255)/256), dim3(256), 0, stream>>>(w2, wsT2, 64);
  k_prepw<<<dim3((16*64*9+255)/256), dim3(256), 0, stream>>>(wm, wsTm, 16);
  k_upsample<<<dim3((NB*CIN*HH*WW+255)/256), dim3(256), 0, stream>>>(x, x0u);
  k_conv3m<64,true,false><<<dim3(3, HH, NB), dim3(256), 0, stream>>>(x0u, wsT1, b1, y1);
  k_conv3m<64,true,false><<<dim3(3, HH, NB), dim3(256), 0, stream>>>(y1, wsT2, b2, x2);
  k_conv3m<16,false,true><<<dim3(3, HH, NB), dim3(256), 0, stream>>>(x2, wsTm, bm, xe);
  k_conv1x1<<<dim3(LL/64, NB), dim3(256), 0, stream>>>(x2, wa, ba, ye);
  k_codes<<<dim3(LL/128, NB), dim3(128), 0, stream>>>(xe, rot, codes);
  k_hist<<<dim3(NSEG, NHASH, NB), dim3(256), 0, stream>>>(codes, segHist);
  k_scan<<<dim3(NB*NHASH), dim3(128), 0, stream>>>(segHist);
  k_rank<<<dim3(NSEG, NHASH, NB), dim3(256), 0, stream>>>(codes, segHist, sortPos, srtIdx);
  k_attn<<<dim3(NCHK, NHASH, NB), dim3(576), AT_LDS, stream>>>(xe, ye, srtIdx, retS, bscore);
  k_combine<<<dim3((NB*LL+255)/256), dim3(256), 0, stream>>>(retS, bscore, sortPos, x2, outp);
}

// Round 5
// 352.336 us; speedup vs baseline: 4.5826x; 1.1688x over previous
//
#include <hip/hip_runtime.h>
#include <math.h>

#define NB 2
#define CIN 64
#define H0 96
#define W0 96
#define HH 192
#define WW 192
#define LL (HH*WW)        // 36864
#define NHASH 4
#define CHK 144
#define NCHK 256          // LL/CHK
#define CE 16
#define CV 64
#define NBUCK 128
#define SEGL 576
#define NSEG 64           // LL/SEGL

// ---- attention LDS layout (bytes) ----
#define K_ROWB   80              // T2: [Kh f0..15 | Kl f0..15 | 16B pad]
#define V_ROWB   912             // 456 bf16 cols (432 keys + 16 zero-pad + 8 pad)
#define P_ROWB   72              // per-q P row: 32 bf16 (64B) + 8B pad (bank spread)
#define KQ_SZB   34560           // 432*80
#define VT_SZB   58368           // 64*912
#define PST_SZB  10368           // 9 waves * 16 * 72
#define LKI_SZB  1728            // 432*4
#define QN_SZB   576             // 144*4
#define LDS_T1   (VT_SZB + PST_SZB + LKI_SZB)                    // 70464
#define LDS_T2   (KQ_SZB + VT_SZB + PST_SZB + LKI_SZB + QN_SZB)  // 105600

typedef __attribute__((ext_vector_type(8))) short short8_t;
typedef __attribute__((ext_vector_type(4))) float f32x4;
union FragU { unsigned int u[4]; int4 i; short8_t s; };

__device__ __forceinline__ unsigned int cvtpk_bf16(float a, float b){
  unsigned int r;
  asm("v_cvt_pk_bf16_f32 %0, %1, %2" : "=v"(r) : "v"(a), "v"(b));
  return r;
}
__device__ __forceinline__ float bfl(unsigned int u){ return __uint_as_float(u << 16); }
__device__ __forceinline__ float bfh(unsigned int u){ return __uint_as_float(u & 0xffff0000u); }

// ---------------- bicubic 2x upsample (separable, edge pad) ----------------
__global__ __launch_bounds__(256) void k_upsample(const float* __restrict__ x,
                                                  float* __restrict__ out){
  int idx = blockIdx.x*256 + threadIdx.x;
  if (idx >= NB*CIN*HH*WW) return;
  int ox = idx % WW; int t2 = idx / WW;
  int oy = t2 % HH;  t2 /= HH;
  int i = oy >> 1, a = oy & 1;
  int j = ox >> 1, b = ox & 1;
  const float e0=-0.03515625f, e1=0.26171875f, e2=0.87890625f, e3=-0.10546875f;
  float wy[4], wx[4]; int ty[4], tx[4];
  if (a){ wy[0]=e3; wy[1]=e2; wy[2]=e1; wy[3]=e0; } else { wy[0]=e0; wy[1]=e1; wy[2]=e2; wy[3]=e3; }
  if (b){ wx[0]=e3; wx[1]=e2; wx[2]=e1; wx[3]=e0; } else { wx[0]=e0; wx[1]=e1; wx[2]=e2; wx[3]=e3; }
  int offy = a ? -1 : -2, offx = b ? -1 : -2;
  #pragma unroll
  for (int k=0;k<4;k++){
    int t = i + offy + k; ty[k] = t<0?0:(t>H0-1?H0-1:t);
    int s = j + offx + k; tx[k] = s<0?0:(s>W0-1?W0-1:s);
  }
  const float* xp = x + (size_t)t2*H0*W0;
  float s = 0.f;
  #pragma unroll
  for (int ky=0;ky<4;ky++){
    const float* row = xp + ty[ky]*W0;
    float rs = 0.f;
    rs = fmaf(wx[0], row[tx[0]], rs);
    rs = fmaf(wx[1], row[tx[1]], rs);
    rs = fmaf(wx[2], row[tx[2]], rs);
    rs = fmaf(wx[3], row[tx[3]], rs);
    s = fmaf(wy[ky], rs, s);
  }
  out[idx] = s;
}

// ---------------- weight prep: fp32 OIHW -> bf16x2 frag layout ---------------
__global__ __launch_bounds__(256) void k_prepw(const float* __restrict__ w,
    unsigned short* __restrict__ wsT, int CO){
  int idx = blockIdx.x*256 + threadIdx.x;
  if (idx >= CO*64*9) return;
  int tap = idx % 9; int rem = idx / 9;
  int ci = rem % 64; int co = rem / 64;
  float v = w[(size_t)(co*64 + ci)*9 + tap];
  unsigned int hu = cvtpk_bf16(v, v) & 0xffffu;
  float hf = bfl(hu);
  unsigned int lu = cvtpk_bf16(v - hf, 0.f) & 0xffffu;
  int half = ci >> 5, kg = (ci >> 3) & 3, e = ci & 7;
  size_t base = ((size_t)(tap*2 + half)*2)*CO*32 + ((size_t)co*4 + kg)*8 + e;
  wsT[base]         = (unsigned short)hu;
  wsT[base + (size_t)CO*32] = (unsigned short)lu;
}

// ---------------- 3x3 conv via MFMA, bf16x3 emulated fp32 --------------------
template<int CO, bool RELU, bool OUT_NLC>
__global__ __launch_bounds__(256) void k_conv3m(const float* __restrict__ in,
    const unsigned short* __restrict__ wsT, const float* __restrict__ bias,
    float* __restrict__ out){
  __shared__ unsigned short inH[3][66][64];
  __shared__ unsigned short inL[3][66][64];
  const int t = threadIdx.x;
  const int bx = blockIdx.x, y = blockIdx.y, n = blockIdx.z;
  const int x0 = bx*64;
  const int l = t & 63, w = t >> 6;
  const int lq = l & 15, kg = l >> 4;

  for (int e = t; e < 3072; e += 256){
    const int chunk = e & 15;
    const int strip = e >> 4;
    const int ci = strip & 63, row = strip >> 6;
    const int gy = y + row - 1;
    float4 v = make_float4(0.f,0.f,0.f,0.f);
    if (gy >= 0 && gy < HH)
      v = *(const float4*)&in[(((size_t)n*CIN + ci)*HH + gy)*WW + x0 + chunk*4];
    float vv[4] = {v.x, v.y, v.z, v.w};
    #pragma unroll
    for (int j = 0; j < 4; ++j){
      const int col = 1 + chunk*4 + j;
      const int sci = (((ci >> 3) ^ (col & 7)) << 3) | (ci & 7);
      unsigned int hu = cvtpk_bf16(vv[j], vv[j]);
      unsigned int lu = cvtpk_bf16(vv[j] - bfl(hu), 0.f);
      inH[row][col][sci] = (unsigned short)hu;
      inL[row][col][sci] = (unsigned short)lu;
    }
  }
  if (t < 192){
    const int ci = t & 63, row = t >> 6;
    const int gy = y + row - 1;
    const bool okY = (gy >= 0 && gy < HH);
    const float* ip = &in[(((size_t)n*CIN + ci)*HH + (size_t)(okY?gy:0))*WW];
    float vL = (okY && x0 >= 1) ? ip[x0-1] : 0.f;
    float vR = (okY && x0+64 < WW) ? ip[x0+64] : 0.f;
    unsigned int hL = cvtpk_bf16(vL, vL);
    unsigned int lLu = cvtpk_bf16(vL - bfl(hL), 0.f);
    unsigned int hR = cvtpk_bf16(vR, vR);
    unsigned int lRu = cvtpk_bf16(vR - bfl(hR), 0.f);
    const int sci0 = ci;
    const int sci65 = (((ci >> 3) ^ 1) << 3) | (ci & 7);
    inH[row][0][sci0]  = (unsigned short)hL;  inL[row][0][sci0]  = (unsigned short)lLu;
    inH[row][65][sci65] = (unsigned short)hR; inL[row][65][sci65] = (unsigned short)lRu;
  }
  __syncthreads();

  constexpr int NCT = CO/16;
  f32x4 acc[NCT];
  #pragma unroll
  for (int c=0;c<NCT;c++) acc[c] = (f32x4){0.f,0.f,0.f,0.f};
  const unsigned short* wlane = wsT + (size_t)lq*32 + (size_t)kg*8;

  #pragma unroll
  for (int tap=0; tap<9; ++tap){
    const int ky = tap/3, kx = tap - ky*3;
    const int col = w*16 + lq + kx;
    #pragma unroll
    for (int half=0; half<2; ++half){
      const int sci = ((((half<<2) | kg) ^ (col & 7)) << 3);
      FragU Bh, Bl;
      Bh.i = *(const int4*)&inH[ky][col][sci];
      Bl.i = *(const int4*)&inL[ky][col][sci];
      const unsigned short* wth = wlane + (size_t)((tap*2+half)*2)*CO*32;
      #pragma unroll
      for (int ct=0; ct<NCT; ++ct){
        FragU Ah, Al;
        Ah.i = *(const int4*)(wth + ct*512);
        Al.i = *(const int4*)(wth + CO*32 + ct*512);
        acc[ct] = __builtin_amdgcn_mfma_f32_16x16x32_bf16(Ah.s, Bl.s, acc[ct], 0,0,0);
        acc[ct] = __builtin_amdgcn_mfma_f32_16x16x32_bf16(Al.s, Bh.s, acc[ct], 0,0,0);
        acc[ct] = __builtin_amdgcn_mfma_f32_16x16x32_bf16(Ah.s, Bh.s, acc[ct], 0,0,0);
      }
    }
  }

  const int px = x0 + w*16 + lq;
  if constexpr (!OUT_NLC){
    #pragma unroll
    for (int ct=0; ct<NCT; ++ct){
      #pragma unroll
      for (int r=0; r<4; ++r){
        const int co = ct*16 + kg*4 + r;
        float v = acc[ct][r] + bias[co];
        if (RELU) v = fmaxf(v, 0.f);
        out[(((size_t)n*CO + co)*HH + y)*WW + px] = v;
      }
    }
  } else {
    #pragma unroll
    for (int r=0; r<4; ++r){
      const int co = kg*4 + r;
      float v = acc[0][r] + bias[co];
      if (RELU) v = fmaxf(v, 0.f);
      out[((size_t)n*LL + y*WW + px)*CO + co] = v;
    }
  }
}

// ---------------- 1x1 conv (ye), output [N][L][64] bf16 ----------------------
__global__ __launch_bounds__(256) void k_conv1x1(const float* __restrict__ x2,
    const float* __restrict__ wa, const float* __restrict__ ba,
    unsigned short* __restrict__ yeB){
  __shared__ float xs[64][64];
  __shared__ float wts[64][64];
  const int t = threadIdx.x;
  const int n = blockIdx.y;
  const int l0 = blockIdx.x*64;
  for (int e=t; e<4096; e+=256){
    int ci = e >> 6, l = e & 63;
    xs[ci][l]  = x2[((size_t)n*CIN+ci)*LL + l0 + l];
    wts[ci][l] = wa[(size_t)l*64 + ci];
  }
  __syncthreads();
  const int l = t & 63, cq = t >> 6;
  float acc[16];
  #pragma unroll
  for (int i=0;i<16;i++) acc[i] = ba[cq*16+i];
  for (int ci=0; ci<64; ci++){
    float xv = xs[ci][l];
    #pragma unroll
    for (int i=0;i<16;i++) acc[i] = fmaf(xv, wts[ci][cq*16+i], acc[i]);
  }
  unsigned int wds[8];
  #pragma unroll
  for (int i=0;i<8;i++) wds[i] = cvtpk_bf16(acc[2*i], acc[2*i+1]);
  uint4* op = (uint4*)&yeB[((size_t)n*LL + l0 + l)*64 + cq*16];
  op[0] = make_uint4(wds[0],wds[1],wds[2],wds[3]);
  op[1] = make_uint4(wds[4],wds[5],wds[6],wds[7]);
}

// ---------------- LSH codes: argmax over [rot ; -rot] ------------------------
__global__ __launch_bounds__(128) void k_codes(const float* __restrict__ xe,
    const float* __restrict__ rot, unsigned char* __restrict__ codes){
  __shared__ float rs[NHASH][64][16];
  const int t = threadIdx.x;
  for (int e=t; e<4096; e+=128){
    int f = e >> 8; int rem = e & 255;
    int h = rem >> 6; int i = rem & 63;
    rs[h][i][f] = rot[((size_t)f*NHASH + h)*64 + i];
  }
  __syncthreads();
  const int n = blockIdx.y;
  const int l = blockIdx.x*128 + t;
  float q[16];
  const float* xr = &xe[((size_t)n*LL + l)*16];
  #pragma unroll
  for (int f=0;f<16;f++) q[f] = xr[f];
  #pragma unroll
  for (int h=0;h<NHASH;h++){
    float bp = -3.0e38f, bn = -3.0e38f; int ap=0, an=0;
    for (int i=0;i<64;i++){
      float s = 0.f;
      #pragma unroll
      for (int f=0;f<16;f++) s = fmaf(q[f], rs[h][i][f], s);
      if (s > bp){ bp = s; ap = i; }
      if (-s > bn){ bn = -s; an = i; }
    }
    int code = (bp >= bn) ? ap : (64 + an);
    codes[((size_t)n*NHASH + h)*LL + l] = (unsigned char)code;
  }
}

// ---------------- stable counting sort: hist / scan / rank+scatter ----------
__global__ __launch_bounds__(256) void k_hist(const unsigned char* __restrict__ codes,
    unsigned int* __restrict__ segHist){
  __shared__ unsigned int h[NBUCK];
  const int t = threadIdx.x;
  if (t < NBUCK) h[t] = 0;
  __syncthreads();
  const int n = blockIdx.z, hh = blockIdx.y, s = blockIdx.x;
  const unsigned char* cp = codes + ((size_t)n*NHASH + hh)*LL + (size_t)s*SEGL;
  for (int e=t; e<SEGL; e+=256) atomicAdd(&h[cp[e]], 1u);
  __syncthreads();
  if (t < NBUCK)
    segHist[(((size_t)(n*NHASH+hh))*NSEG + s)*NBUCK + t] = h[t];
}

__global__ __launch_bounds__(128) void k_scan(unsigned int* __restrict__ segHist){
  __shared__ unsigned int tot[NBUCK];
  __shared__ unsigned int base[NBUCK];
  const int b = threadIdx.x;
  const size_t off = (size_t)blockIdx.x * NSEG * NBUCK;
  unsigned int run = 0;
  for (int s=0;s<NSEG;s++){
    unsigned int v = segHist[off + (size_t)s*NBUCK + b];
    segHist[off + (size_t)s*NBUCK + b] = run;
    run += v;
  }
  tot[b] = run;
  __syncthreads();
  if (b==0){ unsigned int r=0; for (int i=0;i<NBUCK;i++){ base[i]=r; r+=tot[i]; } }
  __syncthreads();
  const unsigned int bb = base[b];
  for (int s=0;s<NSEG;s++) segHist[off + (size_t)s*NBUCK + b] += bb;
}

__global__ __launch_bounds__(256) void k_rank(const unsigned char* __restrict__ codes,
    const unsigned int* __restrict__ segHist, int* __restrict__ sortPos,
    int* __restrict__ srtIdx){
  __shared__ unsigned int cw[SEGL/4];
  __shared__ unsigned int sbase[NBUCK];
  const int t = threadIdx.x;
  const int n = blockIdx.z, hh = blockIdx.y, s = blockIdx.x;
  const size_t cb = ((size_t)n*NHASH + hh)*LL + (size_t)s*SEGL;
  const unsigned int* cp32 = (const unsigned int*)(codes + cb);
  for (int e=t; e<SEGL/4; e+=256) cw[e] = cp32[e];
  if (t < NBUCK)
    sbase[t] = segHist[(((size_t)(n*NHASH+hh))*NSEG + s)*NBUCK + t];
  __syncthreads();
  const size_t ob = ((size_t)n*NHASH + hh)*LL;
  for (int e=t; e<SEGL; e+=256){
    unsigned int c = (cw[e>>2] >> ((e&3)*8)) & 0xffu;
    unsigned int mul = c * 0x01010101u;
    int cnt = 0;
    const int nw = e >> 2;
    for (int wi=0; wi<nw; wi++){
      unsigned int v = cw[wi] ^ mul;
      unsigned int t1 = (v & 0x7f7f7f7fu) + 0x7f7f7f7fu;
      unsigned int z = ~(t1 | v) & 0x80808080u;
      cnt += __popc(z);
    }
    unsigned int lastw = cw[nw];
    const int nbp = e & 3;
    for (int bp=0; bp<nbp; bp++)
      if (((lastw >> (bp*8)) & 0xffu) == c) cnt++;
    int pos = (int)sbase[c] + cnt;
    int l = s*SEGL + e;
    sortPos[ob + l] = pos;
    srtIdx[ob + pos] = l;
  }
}

// ---------------- pre-gather K: normalize + bf16 split, sorted order ---------
__global__ __launch_bounds__(256) void k_gatherK(const float* __restrict__ xe,
    const int* __restrict__ srtIdx, unsigned short* __restrict__ Ksrt,
    float* __restrict__ normQ){
  const int idx = blockIdx.x*256 + threadIdx.x;
  if (idx >= NB*NHASH*LL) return;
  const int n = idx / (NHASH*LL);
  const int lk = srtIdx[idx];
  const float4* xr = (const float4*)&xe[((size_t)n*LL + lk)*16];
  float4 v0 = xr[0], v1 = xr[1], v2 = xr[2], v3 = xr[3];
  float f[16] = {v0.x,v0.y,v0.z,v0.w, v1.x,v1.y,v1.z,v1.w,
                 v2.x,v2.y,v2.z,v2.w, v3.x,v3.y,v3.z,v3.w};
  float ss = 0.f;
  #pragma unroll
  for (int i=0;i<16;i++) ss = fmaf(f[i], f[i], ss);
  const float nq = sqrtf(ss);
  normQ[idx] = nq;
  const float inv = 1.f / fmaxf(nq, 5e-5f);
  #pragma unroll
  for (int i=0;i<16;i++) f[i] *= inv;
  unsigned int kh[8], klo[8];
  #pragma unroll
  for (int i=0;i<8;i++) kh[i] = cvtpk_bf16(f[2*i], f[2*i+1]);
  #pragma unroll
  for (int i=0;i<8;i++)
    klo[i] = cvtpk_bf16(f[2*i] - bfl(kh[i]), f[2*i+1] - bfh(kh[i]));
  int4* kr = (int4*)(Ksrt + (size_t)idx*32);
  kr[0] = make_int4((int)kh[0],(int)kh[1],(int)kh[2],(int)kh[3]);
  kr[1] = make_int4((int)kh[4],(int)kh[5],(int)kh[6],(int)kh[7]);
  kr[2] = make_int4((int)klo[0],(int)klo[1],(int)klo[2],(int)klo[3]);
  kr[3] = make_int4((int)klo[4],(int)klo[5],(int)klo[6],(int)klo[7]);
}

// ---------------- attention v3: single-pass (m = ||q|| analytic) -------------
// TIER 1: K/Q frags from global Ksrt (LDS 70.5KB -> 2 blocks/CU)
// TIER 2: K staged in LDS from xe (as R4; LDS 105.6KB)
// S = mscale * (Ki . Kq), mscale = max(||q||,5e-5); m = ||q|| (self-key => exact max)
template<int TIER>
__global__ __launch_bounds__(576) void k_attn2(const float* __restrict__ xe,
    const unsigned short* __restrict__ yeB, const int* __restrict__ srtIdx,
    const unsigned short* __restrict__ Ksrt, const float* __restrict__ normQ,
    unsigned short* __restrict__ retS, float* __restrict__ bscore){
  extern __shared__ char smem[];
  constexpr int KQOFF = (TIER==2) ? KQ_SZB : 0;
  unsigned short* Kq = (unsigned short*)smem;            // T2 only
  char* Vt  = smem + KQOFF;
  char* Pst = Vt + VT_SZB;
  int* lkI  = (int*)(Pst + PST_SZB);
  float* qn = (float*)(Pst + PST_SZB + LKI_SZB);         // T2 only

  const int t = threadIdx.x;
  const int k = blockIdx.x, hh = blockIdx.y, n = blockIdx.z;
  const size_t sb = ((size_t)n*NHASH + hh)*LL;
  const int l = t & 63, w = t >> 6;
  const int lq16 = l & 15, g = l >> 4;

  // ---- phase 0 ----
  if (t < 432){
    const int c3 = t / CHK, jl = t - c3*CHK;
    const int kc = (c3==0) ? k : ((c3==1) ? ((k+NCHK-1)&(NCHK-1)) : ((k+1)&(NCHK-1)));
    const int lk = srtIdx[sb + (size_t)kc*CHK + jl];
    lkI[t] = lk;
    if constexpr (TIER==2){
      const float4* xr = (const float4*)&xe[((size_t)n*LL + lk)*16];
      float4 v0 = xr[0], v1 = xr[1], v2 = xr[2], v3 = xr[3];
      float f[16] = {v0.x,v0.y,v0.z,v0.w, v1.x,v1.y,v1.z,v1.w,
                     v2.x,v2.y,v2.z,v2.w, v3.x,v3.y,v3.z,v3.w};
      float ss = 0.f;
      #pragma unroll
      for (int i=0;i<16;i++) ss = fmaf(f[i], f[i], ss);
      const float nq = sqrtf(ss);
      if (c3 == 0) qn[jl] = nq;
      const float inv = 1.f / fmaxf(nq, 5e-5f);
      #pragma unroll
      for (int i=0;i<16;i++) f[i] *= inv;
      unsigned int kh[8], klo[8];
      #pragma unroll
      for (int i=0;i<8;i++) kh[i] = cvtpk_bf16(f[2*i], f[2*i+1]);
      #pragma unroll
      for (int i=0;i<8;i++)
        klo[i] = cvtpk_bf16(f[2*i] - bfl(kh[i]), f[2*i+1] - bfh(kh[i]));
      int4* kr = (int4*)((char*)Kq + t*K_ROWB);
      kr[0] = make_int4((int)kh[0],(int)kh[1],(int)kh[2],(int)kh[3]);
      kr[1] = make_int4((int)kh[4],(int)kh[5],(int)kh[6],(int)kh[7]);
      kr[2] = make_int4((int)klo[0],(int)klo[1],(int)klo[2],(int)klo[3]);
      kr[3] = make_int4((int)klo[4],(int)klo[5],(int)klo[6],(int)klo[7]);
    }
  }
  if (t < 512){
    int c = t >> 3, jp = t & 7;
    *(unsigned int*)(Vt + c*V_ROWB + 864 + jp*4) = 0u;
  }
  __syncthreads();

  // ---- V stage (bf16 source) + Q frags ----
  #pragma unroll 4
  for (int it=0; it<24; ++it){
    const int e = t + it*576;
    const int jp = e >> 6, c = e & 63;
    const unsigned int a = yeB[((size_t)n*LL + lkI[2*jp  ])*64 + c];
    const unsigned int b = yeB[((size_t)n*LL + lkI[2*jp+1])*64 + c];
    *(unsigned int*)(Vt + c*V_ROWB + jp*4) = a | (b << 16);
  }
  const int qg = w*16 + lq16;
  const int pq = k*CHK + qg;
  FragU b1, b2;
  float nq_;
  if constexpr (TIER==1){
    const unsigned short* qrow = Ksrt + (sb + pq)*32;
    b1.i = *(const int4*)(qrow + (g&1)*8);
    if (g < 2) b2.i = *(const int4*)(qrow + 16 + (g&1)*8);
    else { b2.u[0]=0u; b2.u[1]=0u; b2.u[2]=0u; b2.u[3]=0u; }
    nq_ = normQ[sb + pq];
  } else {
    const char* qrow = (const char*)Kq + qg*K_ROWB;
    b1.i = *(const int4*)(qrow + (g&1)*16);
    if (g < 2) b2.i = *(const int4*)(qrow + 32 + (g&1)*16);
    else { b2.u[0]=0u; b2.u[1]=0u; b2.u[2]=0u; b2.u[3]=0u; }
    nq_ = qn[qg];
  }
  const float msc = fmaxf(nq_, 5e-5f);
  __syncthreads();

  // ---- single pass: S tiles -> P -> O^T = V^T P^T ----
  float sum = 0.f;
  f32x4 O0 = {0.f,0.f,0.f,0.f}, O1 = O0, O2 = O0, O3 = O0;
  char* Pw = Pst + w*(16*P_ROWB);
  for (int u=0; u<14; ++u){
    #pragma unroll
    for (int sub=0; sub<2; ++sub){
      const int t27 = u*2 + sub;
      uint2 pw;
      if (t27 < 27){
        FragU a;
        if constexpr (TIER==1){
          const int c3 = t27 / 9;
          const int kc = (c3==0) ? k : ((c3==1) ? ((k+NCHK-1)&(NCHK-1)) : ((k+1)&(NCHK-1)));
          const int row16 = (t27 - c3*9)*16;
          a.i = *(const int4*)(Ksrt + (sb + (size_t)kc*CHK + row16 + lq16)*32 + g*8);
        } else {
          a.i = *(const int4*)((const char*)Kq + (size_t)(t27*16 + lq16)*K_ROWB + g*16);
        }
        f32x4 C = {0.f,0.f,0.f,0.f};
        C = __builtin_amdgcn_mfma_f32_16x16x32_bf16(a.s, b2.s, C, 0, 0, 0);
        C = __builtin_amdgcn_mfma_f32_16x16x32_bf16(a.s, b1.s, C, 0, 0, 0);
        const float p0 = __expf(fmaf(msc, C[0], -nq_));
        const float p1 = __expf(fmaf(msc, C[1], -nq_));
        const float p2 = __expf(fmaf(msc, C[2], -nq_));
        const float p3 = __expf(fmaf(msc, C[3], -nq_));
        sum += (p0+p1) + (p2+p3);
        pw = make_uint2(cvtpk_bf16(p0,p1), cvtpk_bf16(p2,p3));
      } else {
        pw = make_uint2(0u, 0u);
      }
      *(uint2*)(Pw + lq16*P_ROWB + sub*32 + g*8) = pw;
    }
    asm volatile("s_waitcnt lgkmcnt(0)" ::: "memory");
    __builtin_amdgcn_sched_barrier(0);
    FragU bp; bp.i = *(const int4*)(Pw + lq16*P_ROWB + g*16);
    const char* Vb = Vt + lq16*V_ROWB + u*64 + g*16;
    FragU av;
    av.i = *(const int4*)(Vb);             O0 = __builtin_amdgcn_mfma_f32_16x16x32_bf16(av.s, bp.s, O0, 0,0,0);
    av.i = *(const int4*)(Vb + 16*V_ROWB); O1 = __builtin_amdgcn_mfma_f32_16x16x32_bf16(av.s, bp.s, O1, 0,0,0);
    av.i = *(const int4*)(Vb + 32*V_ROWB); O2 = __builtin_amdgcn_mfma_f32_16x16x32_bf16(av.s, bp.s, O2, 0,0,0);
    av.i = *(const int4*)(Vb + 48*V_ROWB); O3 = __builtin_amdgcn_mfma_f32_16x16x32_bf16(av.s, bp.s, O3, 0,0,0);
  }
  sum += __shfl_xor(sum, 16);
  sum += __shfl_xor(sum, 32);
  const float linv = 1.f / sum;

  unsigned short* op = &retS[(sb + pq)*64];
  {
    uint2 s0 = make_uint2(cvtpk_bf16(O0[0]*linv, O0[1]*linv), cvtpk_bf16(O0[2]*linv, O0[3]*linv));
    uint2 s1 = make_uint2(cvtpk_bf16(O1[0]*linv, O1[1]*linv), cvtpk_bf16(O1[2]*linv, O1[3]*linv));
    uint2 s2 = make_uint2(cvtpk_bf16(O2[0]*linv, O2[1]*linv), cvtpk_bf16(O2[2]*linv, O2[3]*linv));
    uint2 s3 = make_uint2(cvtpk_bf16(O3[0]*linv, O3[1]*linv), cvtpk_bf16(O3[2]*linv, O3[3]*linv));
    *(uint2*)(op +  0 + g*4) = s0;
    *(uint2*)(op + 16 + g*4) = s1;
    *(uint2*)(op + 32 + g*4) = s2;
    *(uint2*)(op + 48 + g*4) = s3;
  }
  if (g == 0) bscore[sb + pq] = nq_ + logf(sum);
}

// ---------------- unsort + hash-softmax combine + residual -------------------
__global__ __launch_bounds__(256) void k_combine(const unsigned short* __restrict__ retS,
    const float* __restrict__ bscore, const int* __restrict__ sortPos,
    const float* __restrict__ x2, float* __restrict__ out){
  const int idx = blockIdx.x*256 + threadIdx.x;
  if (idx >= NB*LL) return;
  const int l = idx % LL, n = idx / LL;
  float bs[NHASH]; int pp[NHASH];
  #pragma unroll
  for (int h=0;h<NHASH;h++){
    size_t sb = ((size_t)n*NHASH + h)*LL;
    int p = sortPos[sb + l];
    pp[h] = p; bs[h] = bscore[sb + p];
  }
  float m = fmaxf(fmaxf(bs[0],bs[1]), fmaxf(bs[2],bs[3]));
  float wsum = 0.f; float wv[NHASH];
  #pragma unroll
  for (int h=0;h<NHASH;h++){ wv[h] = expf(bs[h]-m); wsum += wv[h]; }
  const float winv = 1.f / wsum;
  float o[64];
  #pragma unroll
  for (int i=0;i<64;i++) o[i]=0.f;
  #pragma unroll
  for (int h=0;h<NHASH;h++){
    const float wh = wv[h]*winv;
    const uint4* rp = (const uint4*)&retS[(((size_t)n*NHASH + h)*LL + pp[h])*64];
    #pragma unroll
    for (int i2=0;i2<8;i2++){
      uint4 v = rp[i2];
      o[i2*8+0] = fmaf(wh, bfl(v.x), o[i2*8+0]);
      o[i2*8+1] = fmaf(wh, bfh(v.x), o[i2*8+1]);
      o[i2*8+2] = fmaf(wh, bfl(v.y), o[i2*8+2]);
      o[i2*8+3] = fmaf(wh, bfh(v.y), o[i2*8+3]);
      o[i2*8+4] = fmaf(wh, bfl(v.z), o[i2*8+4]);
      o[i2*8+5] = fmaf(wh, bfh(v.z), o[i2*8+5]);
      o[i2*8+6] = fmaf(wh, bfl(v.w), o[i2*8+6]);
      o[i2*8+7] = fmaf(wh, bfh(v.w), o[i2*8+7]);
    }
  }
  #pragma unroll
  for (int c=0;c<64;c++){
    size_t oi = ((size_t)n*64 + c)*LL + l;
    out[oi] = o[c] + x2[oi];
  }
}

extern "C" void kernel_launch(void* const* d_in, const int* in_sizes, int n_in,
                              void* d_out, int out_size, void* d_ws, size_t ws_size,
                              hipStream_t stream){
  const float* x   = (const float*)d_in[0];
  const float* w1  = (const float*)d_in[1];
  const float* b1  = (const float*)d_in[2];
  const float* w2  = (const float*)d_in[3];
  const float* b2  = (const float*)d_in[4];
  const float* wm  = (const float*)d_in[5];
  const float* bm  = (const float*)d_in[6];
  const float* wa  = (const float*)d_in[7];
  const float* ba  = (const float*)d_in[8];
  const float* rot = (const float*)d_in[9];
  float* outp = (float*)d_out;
  char* ws = (char*)d_ws;
  const size_t FM   = (size_t)NB*CIN*HH*WW*sizeof(float);        // 18,874,368
  const size_t YEB  = (size_t)NB*LL*64*2;                        //  9,437,184
  const size_t RETB = (size_t)NB*NHASH*LL*64*2;                  // 37,748,736
  const size_t NHL4 = (size_t)NB*NHASH*LL*4;                     //  1,179,648

  char* p = ws;
  unsigned short* yeB = (unsigned short*)p;  p += YEB;
  char* regA = p;                            p += RETB;          // retS; convs' x0u/y1 live here
  float* x2  = (float*)p;                    p += FM;
  float* xe  = (float*)p;                    p += (size_t)NB*LL*CE*sizeof(float);
  unsigned char* codes = (unsigned char*)p;  p += (size_t)NB*NHASH*LL;
  unsigned int* segHist = (unsigned int*)p;  p += (size_t)NB*NHASH*NSEG*NBUCK*4;
  int* sortPos = (int*)p;                    p += NHL4;
  int* srtIdx  = (int*)p;                    p += NHL4;
  float* bscore = (float*)p;                 p += NHL4;
  unsigned short* wsT1 = (unsigned short*)p; p += (size_t)9*2*2*64*32*2;
  unsigned short* wsT2 = (unsigned short*)p; p += (size_t)9*2*2*64*32*2;
  unsigned short* wsTm = (unsigned short*)p; p += (size_t)9*2*2*16*32*2;
  const size_t needT2 = (size_t)(p - ws);
  unsigned short* Ksrt = (unsigned short*)p; p += (size_t)NB*NHASH*LL*32*2;
  float* normQ = (float*)p;                  p += NHL4;
  const size_t needT1 = (size_t)(p - ws);

  unsigned short* retS = (unsigned short*)regA;
  float* x0u = (float*)regA;
  float* y1  = (float*)(regA + FM);
  if (ws_size < needT2) return;
  const bool preg = (ws_size >= needT1);

  hipFuncSetAttribute((const void*)k_attn2<1>,
                      hipFuncAttributeMaxDynamicSharedMemorySize, LDS_T1);
  hipFuncSetAttribute((const void*)k_attn2<2>,
                      hipFuncAttributeMaxDynamicSharedMemorySize, LDS_T2);

  k_prepw<<<dim3((64*64*9+255)/256), dim3(256), 0, stream>>>(w1, wsT1, 64);
  k_prepw<<<dim3((64*64*9+255)/256), dim3(256), 0, stream>>>(w2, wsT2, 64);
  k_prepw<<<dim3((16*64*9+255)/256), dim3(256), 0, stream>>>(wm, wsTm, 16);
  k_upsample<<<dim3((NB*CIN*HH*WW+255)/256), dim3(256), 0, stream>>>(x, x0u);
  k_conv3m<64,true,false><<<dim3(3, HH, NB), dim3(256), 0, stream>>>(x0u, wsT1, b1, y1);
  k_conv3m<64,true,false><<<dim3(3, HH, NB), dim3(256), 0, stream>>>(y1, wsT2, b2, x2);
  k_conv3m<16,false,true><<<dim3(3, HH, NB), dim3(256), 0, stream>>>(x2, wsTm, bm, xe);
  k_conv1x1<<<dim3(LL/64, NB), dim3(256), 0, stream>>>(x2, wa, ba, yeB);
  k_codes<<<dim3(LL/128, NB), dim3(128), 0, stream>>>(xe, rot, codes);
  k_hist<<<dim3(NSEG, NHASH, NB), dim3(256), 0, stream>>>(codes, segHist);
  k_scan<<<dim3(NB*NHASH), dim3(128), 0, stream>>>(segHist);
  k_rank<<<dim3(NSEG, NHASH, NB), dim3(256), 0, stream>>>(codes, segHist, sortPos, srtIdx);
  if (preg){
    k_gatherK<<<dim3((NB*NHASH*LL+255)/256), dim3(256), 0, stream>>>(xe, srtIdx, Ksrt, normQ);
    k_attn2<1><<<dim3(NCHK, NHASH, NB), dim3(576), LDS_T1, stream>>>(
        xe, yeB, srtIdx, Ksrt, normQ, retS, bscore);
  } else {
    k_attn2<2><<<dim3(NCHK, NHASH, NB), dim3(576), LDS_T2, stream>>>(
        xe, yeB, srtIdx, Ksrt, normQ, retS, bscore);
  }
  k_combine<<<dim3((NB*LL+255)/256), dim3(256), 0, stream>>>(retS, bscore, sortPos, x2, outp);
}